// Round 1
// 337.657 us; speedup vs baseline: 1.0654x; 1.0654x over previous
//
#include <hip/hip_runtime.h>
#include <hip/hip_bf16.h>

#define B_   2
#define T_   2048
#define DM_  2048
#define HQ_  32
#define HKV_ 8
#define HD_  64

typedef __attribute__((ext_vector_type(8))) short bf16x8;
typedef __attribute__((ext_vector_type(4))) float f32x4;
typedef __fp16 f16x4 __attribute__((ext_vector_type(4)));
typedef __fp16 f16x2 __attribute__((ext_vector_type(2)));

__device__ __forceinline__ unsigned short f2bf(float f) {
    unsigned int u = __float_as_uint(f);
    u = (u + 0x7fffu + ((u >> 16) & 1u)) >> 16;   // RNE
    return (unsigned short)u;
}

__device__ __forceinline__ void gload16(const unsigned short* g, unsigned short* l) {
    __builtin_amdgcn_global_load_lds(
        (const __attribute__((address_space(1))) unsigned int*)g,
        (__attribute__((address_space(3))) unsigned int*)l, 16, 0, 0);
}

// ---------------------------------------------------------------------------
// Workspace (ushort elements, 76 MiB total):
//   xb  : 8388608   (4096,2048)      bf16 x
//   Wb  : 6291456   (3072,2048)      bf16 [WQ;WK;WV]
//   WOb : 4194304   (2048,2048)      bf16 WO
//   Qb  : 8388608   (B,HQ,T,HD)      bf16 Q (RoPE'd in place, scaled log2e/8)
//   Kb  : 2097152   (B,HKV,T,HD)     bf16 K (RoPE'd in place)
//   Vt  : 2097152   (B,HKV,HD,T)     f16 V transposed
//   Ob  : 8388608   (B,T,HQ*HD)      bf16 attention out
// ---------------------------------------------------------------------------

// ---------------- merged fp32 -> bf16 convert (x, WQ, WK, WV, WO) ----------
__global__ __launch_bounds__(256) void convert_all(
    const float* __restrict__ x,  const float* __restrict__ WQ,
    const float* __restrict__ WK, const float* __restrict__ WV,
    const float* __restrict__ WO, unsigned short* __restrict__ ws)
{
    int i = blockIdx.x*256 + threadIdx.x;        // float4 index, total 4718592
    const float* src; unsigned short* dst; int rel;
    if (i < 2097152)      { src = x;  dst = ws;                 rel = i; }
    else if (i < 3145728) { src = WQ; dst = ws + 8388608;       rel = i - 2097152; }
    else if (i < 3407872) { src = WK; dst = ws + 8388608+4194304; rel = i - 3145728; }
    else if (i < 3670016) { src = WV; dst = ws + 8388608+5242880; rel = i - 3407872; }
    else                  { src = WO; dst = ws + 14680064;      rel = i - 3670016; }
    float4 v = *(const float4*)(src + (size_t)rel*4);
    uint2 pk;
    pk.x = (unsigned int)f2bf(v.x) | ((unsigned int)f2bf(v.y) << 16);
    pk.y = (unsigned int)f2bf(v.z) | ((unsigned int)f2bf(v.w) << 16);
    *(uint2*)(dst + (size_t)rel*4) = pk;
}

// ---------------- QKV projection: bf16 MFMA GEMM ----------
__global__ __launch_bounds__(256) void qkv_gemm_bf16(
    const unsigned short* __restrict__ Ab, const unsigned short* __restrict__ Wb,
    unsigned short* __restrict__ Qb, unsigned short* __restrict__ Kb,
    unsigned short* __restrict__ Vt)
{
    __shared__ unsigned short As[128*32];
    __shared__ unsigned short Bs[128*32];
    const int tid  = threadIdx.x;
    const int ln   = tid & 63;
    const int wv   = tid >> 6;
    const int wm   = (wv >> 1) * 64;
    const int wn   = (wv & 1) * 64;
    const int col  = ln & 15;
    const int quad = ln >> 4;
    const int m0   = blockIdx.y * 128;
    const int n0   = blockIdx.x * 128;

    const unsigned short* aG = Ab + (size_t)(m0 + (tid>>2))*DM_ + (tid&3)*8;
    const unsigned short* bG = Wb + (size_t)(n0 + (tid>>2))*DM_ + (tid&3)*8;
    unsigned short* aL0 = &As[wv*512];
    unsigned short* aL1 = &As[wv*512 + 2048];
    unsigned short* bL0 = &Bs[wv*512];
    unsigned short* bL1 = &Bs[wv*512 + 2048];

    f32x4 acc[4][4];
    #pragma unroll
    for (int i=0;i<4;++i)
        #pragma unroll
        for (int j=0;j<4;++j) { acc[i][j][0]=0.f; acc[i][j][1]=0.f; acc[i][j][2]=0.f; acc[i][j][3]=0.f; }

    for (int k0 = 0; k0 < DM_; k0 += 32) {
        __syncthreads();
        gload16(aG + k0,                  aL0);
        gload16(aG + (size_t)64*DM_ + k0, aL1);
        gload16(bG + k0,                  bL0);
        gload16(bG + (size_t)64*DM_ + k0, bL1);
        __syncthreads();
        bf16x8 af[4], bfr[4];
        #pragma unroll
        for (int i=0;i<4;++i) {
            af[i]  = *(const bf16x8*)&As[(wm + i*16 + col)*32 + quad*8];
            bfr[i] = *(const bf16x8*)&Bs[(wn + i*16 + col)*32 + quad*8];
        }
        #pragma unroll
        for (int i=0;i<4;++i)
            #pragma unroll
            for (int j=0;j<4;++j)
                acc[i][j] = __builtin_amdgcn_mfma_f32_16x16x32_bf16(af[i], bfr[j], acc[i][j], 0, 0, 0);
    }

    const int b  = m0 >> 11;
    const int tb = m0 & 2047;
    #pragma unroll
    for (int j=0;j<4;++j) {
        const int n = n0 + wn + j*16 + col;
        #pragma unroll
        for (int i=0;i<4;++i) {
            const int t = tb + wm + i*16 + quad*4;
            if (n < 2048) {
                #pragma unroll
                for (int r=0;r<4;++r)
                    Qb[(((size_t)(b*HQ_ + (n>>6)))*T_ + t + r)*HD_ + (n&63)] = f2bf(acc[i][j][r]);
            } else if (n < 2560) {
                #pragma unroll
                for (int r=0;r<4;++r)
                    Kb[(((size_t)(b*HKV_ + ((n-2048)>>6)))*T_ + t + r)*HD_ + (n&63)] = f2bf(acc[i][j][r]);
            } else {
                unsigned short* vp = Vt + (((size_t)(b*HKV_ + ((n-2560)>>6)))*HD_ + (n&63))*T_ + t;
                union { f16x2 h; unsigned int u; } c0, c1;
                c0.h = __builtin_amdgcn_cvt_pkrtz(acc[i][j][0], acc[i][j][1]);
                c1.h = __builtin_amdgcn_cvt_pkrtz(acc[i][j][2], acc[i][j][3]);
                *(unsigned int*)(vp)     = c0.u;
                *(unsigned int*)(vp + 2) = c1.u;
            }
        }
    }
}

// ---------------- RoPE in place; Q scaled by log2(e)/8 ----------------
__global__ __launch_bounds__(256) void rope_inplace(
    unsigned short* __restrict__ Qb, unsigned short* __restrict__ Kb,
    const int* __restrict__ pos)
{
    const int NQ = B_*HQ_*T_*(HD_/2);
    const int NK = B_*HKV_*T_*(HD_/2);
    int idx = blockIdx.x*256 + threadIdx.x;
    unsigned short* base; float scale;
    int rem;
    if (idx < NQ) { base = Qb; rem = idx; scale = 0.18033688011112042f; }  // log2(e)/8
    else { rem = idx - NQ; if (rem >= NK) return; base = Kb; scale = 1.0f; }
    const int i  = rem & 31;
    const int t  = (rem >> 5) & (T_ - 1);
    const int bh = rem >> 16;
    size_t off = (((size_t)bh)*T_ + t)*HD_ + (i<<1);
    unsigned int pk = *(unsigned int*)(base + off);
    float x1 = __uint_as_float((pk & 0xffffu) << 16);
    float x2 = __uint_as_float(pk & 0xffff0000u);
    float p = (float)pos[t];
    float inv = exp2f(-13.287712379549449f * ((float)(i<<1)) * (1.0f/64.0f));
    float ang = p * inv;
    float sn, cs;
    sincosf(ang, &sn, &cs);
    float r1 = (x1*cs - x2*sn) * scale;
    float r2 = (x1*sn + x2*cs) * scale;
    unsigned int out = (unsigned int)f2bf(r1) | ((unsigned int)f2bf(r2) << 16);
    *(unsigned int*)(base + off) = out;
}

// ---------------- MFMA flash attention, paired Q-tiles, pipelined ----------
// Fixed-max softmax as before (p = exp2(s), 1/l normalize at end).
// R8 vs R7: LDS double-buffer -> ONE barrier per kv-tile (staging ds_writes
// drain under compute); kt loop split into a branchless both-states phase
// (kt<=qa; qa<qbt always holds) and a B-only phase, removing the `if(doA)` BB
// splits that blocked MFMA/VALU co-scheduling; SM-B interleaved under QK-A
// MFMAs and SM-A under the PV MFMAs; s_setprio(1) around compute (T5).
__global__ __launch_bounds__(256, 2) void attn_mfma(
    const unsigned short* __restrict__ Qb, const unsigned short* __restrict__ Kb,
    const unsigned short* __restrict__ Vh, unsigned short* __restrict__ Ob)
{
    __shared__ unsigned short Ks[2][64*64];    // bf16 K rows (k), d chunks swizzled
    __shared__ unsigned short Vs[2][64*64];    // f16 V^T rows (d), k chunks swizzled

    const int tid  = threadIdx.x;
    const int lane = tid & 63;
    const int wave = tid >> 6;
    const int q16  = lane & 15;
    const int quad = lane >> 4;
    const int bxi  = blockIdx.x;          // 0..15
    const int bh   = blockIdx.y;
    const int b    = bh >> 5;
    const int h    = bh & 31;
    const int kvh  = h >> 2;
    const int qa   = bxi;                 // 0..15
    const int qbt  = 31 - bxi;            // 16..31 (qa < qbt always)
    const int qgA  = qa *64 + wave*16 + q16;
    const int qgB  = qbt*64 + wave*16 + q16;

    const unsigned short* kbase = Kb + ((size_t)(b*HKV_ + kvh))*T_*HD_;
    const unsigned short* vbase = Vh + ((size_t)(b*HKV_ + kvh))*(size_t)HD_*T_;

    const bf16x8 qA0 = *(const bf16x8*)(Qb + ((size_t)bh*T_ + qgA)*HD_ + quad*8);
    const bf16x8 qA1 = *(const bf16x8*)(Qb + ((size_t)bh*T_ + qgA)*HD_ + 32 + quad*8);
    const bf16x8 qB0 = *(const bf16x8*)(Qb + ((size_t)bh*T_ + qgB)*HD_ + quad*8);
    const bf16x8 qB1 = *(const bf16x8*)(Qb + ((size_t)bh*T_ + qgB)*HD_ + 32 + quad*8);

    f32x4 oA[4], oB[4];
    #pragma unroll
    for (int i=0;i<4;++i) {
        oA[i][0]=0.f; oA[i][1]=0.f; oA[i][2]=0.f; oA[i][3]=0.f;
        oB[i][0]=0.f; oB[i][1]=0.f; oB[i][2]=0.f; oB[i][3]=0.f;
    }
    float lA = 0.f, lB = 0.f;

    // staging: thread covers rows sr, sr+32, chunk sj; swizzled col sc
    const int sr = tid >> 3;              // 0..31
    const int sj = tid & 7;               // 16B chunk
    const int sc = (sj ^ (sr & 7)) * 8;   // (sr+32)&7 == sr&7

    // swizzled read columns (row&7 == q16&7 for all fragment rows)
    const int rk7 = q16 & 7;
    const int ck0 = (quad ^ rk7) * 8;
    const int ck1 = ((quad + 4) ^ rk7) * 8;

    auto smrow = [&](const f32x4 s, float& ps) -> f16x4 {
        float e0 = exp2f(s[0]), e1 = exp2f(s[1]);
        float e2 = exp2f(s[2]), e3 = exp2f(s[3]);
        ps += (e0+e1) + (e2+e3);
        union { f16x2 h[2]; f16x4 v; } c;
        c.h[0] = __builtin_amdgcn_cvt_pkrtz(e0, e1);
        c.h[1] = __builtin_amdgcn_cvt_pkrtz(e2, e3);
        return c.v;
    };

    uint4 kr0, kr1, vr0, vr1;
    // tile 0: load + stage into buf 0
    kr0 = *(const uint4*)(kbase + (size_t)sr*HD_ + sj*8);
    kr1 = *(const uint4*)(kbase + (size_t)(sr+32)*HD_ + sj*8);
    vr0 = *(const uint4*)(vbase + (size_t)sr*T_ + sj*8);
    vr1 = *(const uint4*)(vbase + (size_t)(sr+32)*T_ + sj*8);
    *(uint4*)&Ks[0][sr*64 + sc]      = kr0;
    *(uint4*)&Ks[0][(sr+32)*64 + sc] = kr1;
    *(uint4*)&Vs[0][sr*64 + sc]      = vr0;
    *(uint4*)&Vs[0][(sr+32)*64 + sc] = vr1;
    // prefetch tile 1 (always exists: qbt >= 16)
    kr0 = *(const uint4*)(kbase + (size_t)(64+sr)*HD_ + sj*8);
    kr1 = *(const uint4*)(kbase + (size_t)(64+sr+32)*HD_ + sj*8);
    vr0 = *(const uint4*)(vbase + (size_t)sr*T_ + 64 + sj*8);
    vr1 = *(const uint4*)(vbase + (size_t)(sr+32)*T_ + 64 + sj*8);
    __syncthreads();

    int cur = 0;

    // ---- phase 1: both Q-states (kt <= qa < qbt), branchless body ----------
    for (int kt = 0; kt <= qa; ++kt) {
        const unsigned short* KsC = Ks[cur];
        const unsigned short* VsC = Vs[cur];
        const int nxt = cur ^ 1;

        f32x4 sB[4], sA[4];
        #pragma unroll
        for (int t=0;t<4;++t) {
            sB[t][0]=0.f; sB[t][1]=0.f; sB[t][2]=0.f; sB[t][3]=0.f;
            sA[t][0]=0.f; sA[t][1]=0.f; sA[t][2]=0.f; sA[t][3]=0.f;
        }
        f16x4 pfB[4];
        float psB = 0.f, psA = 0.f;

        __builtin_amdgcn_s_setprio(1);
        #pragma unroll
        for (int t = 0; t < 4; ++t) {
            const int rk = (t*16 + q16) * 64;
            bf16x8 a0 = *(const bf16x8*)&KsC[rk + ck0];
            bf16x8 a1 = *(const bf16x8*)&KsC[rk + ck1];
            sB[t] = __builtin_amdgcn_mfma_f32_16x16x32_bf16(a0, qB0, sB[t], 0, 0, 0);
            sB[t] = __builtin_amdgcn_mfma_f32_16x16x32_bf16(a1, qB1, sB[t], 0, 0, 0);
            sA[t] = __builtin_amdgcn_mfma_f32_16x16x32_bf16(a0, qA0, sA[t], 0, 0, 0);
            sA[t] = __builtin_amdgcn_mfma_f32_16x16x32_bf16(a1, qA1, sA[t], 0, 0, 0);
            if (t > 0) pfB[t-1] = smrow(sB[t-1], psB);
        }
        // stage tile kt+1 into buf^1 (always exists: kt+1 <= qa+1 <= qbt)
        *(uint4*)&Ks[nxt][sr*64 + sc]      = kr0;
        *(uint4*)&Ks[nxt][(sr+32)*64 + sc] = kr1;
        *(uint4*)&Vs[nxt][sr*64 + sc]      = vr0;
        *(uint4*)&Vs[nxt][(sr+32)*64 + sc] = vr1;
        if (kt + 1 < qbt) {
            const int kn = (kt+2)*64;
            kr0 = *(const uint4*)(kbase + (size_t)(kn+sr)*HD_ + sj*8);
            kr1 = *(const uint4*)(kbase + (size_t)(kn+sr+32)*HD_ + sj*8);
            vr0 = *(const uint4*)(vbase + (size_t)sr*T_ + kn + sj*8);
            vr1 = *(const uint4*)(vbase + (size_t)(sr+32)*T_ + kn + sj*8);
        }
        pfB[3] = smrow(sB[3], psB);
        lB += psB;

        if (kt == qa) {   // causal boundary for state A (last phase-1 iter)
            #pragma unroll
            for (int t = 0; t < 4; ++t)
                #pragma unroll
                for (int r = 0; r < 4; ++r)
                    if (kt*64 + t*16 + quad*4 + r > qgA) sA[t][r] = -1e30f;
        }

        // PV both states, t-outer; SM-A[t] between oB and oA MFMA groups
        #pragma unroll
        for (int t = 0; t < 4; ++t) {
            const int cv = ((2*t + (quad>>1)) ^ rk7) * 8 + (quad&1)*4;
            f16x4 va[4];
            #pragma unroll
            for (int dt=0;dt<4;++dt)
                va[dt] = *(const f16x4*)&VsC[(dt*16 + q16)*64 + cv];
            #pragma unroll
            for (int dt=0;dt<4;++dt)
                oB[dt] = __builtin_amdgcn_mfma_f32_16x16x16f16(va[dt], pfB[t], oB[dt], 0, 0, 0);
            f16x4 pfA = smrow(sA[t], psA);
            #pragma unroll
            for (int dt=0;dt<4;++dt)
                oA[dt] = __builtin_amdgcn_mfma_f32_16x16x16f16(va[dt], pfA, oA[dt], 0, 0, 0);
        }
        lA += psA;
        __builtin_amdgcn_s_setprio(0);
        __syncthreads();
        cur ^= 1;
    }

    // ---- phase 2: state B only (qa < kt <= qbt) ----------------------------
    for (int kt = qa+1; kt <= qbt; ++kt) {
        const unsigned short* KsC = Ks[cur];
        const unsigned short* VsC = Vs[cur];
        const int nxt = cur ^ 1;

        f32x4 sB[4];
        #pragma unroll
        for (int t=0;t<4;++t) { sB[t][0]=0.f; sB[t][1]=0.f; sB[t][2]=0.f; sB[t][3]=0.f; }

        __builtin_amdgcn_s_setprio(1);
        #pragma unroll
        for (int t = 0; t < 4; ++t) {
            const int rk = (t*16 + q16) * 64;
            bf16x8 a0 = *(const bf16x8*)&KsC[rk + ck0];
            bf16x8 a1 = *(const bf16x8*)&KsC[rk + ck1];
            sB[t] = __builtin_amdgcn_mfma_f32_16x16x32_bf16(a0, qB0, sB[t], 0, 0, 0);
            sB[t] = __builtin_amdgcn_mfma_f32_16x16x32_bf16(a1, qB1, sB[t], 0, 0, 0);
        }
        if (kt < qbt) {
            *(uint4*)&Ks[nxt][sr*64 + sc]      = kr0;
            *(uint4*)&Ks[nxt][(sr+32)*64 + sc] = kr1;
            *(uint4*)&Vs[nxt][sr*64 + sc]      = vr0;
            *(uint4*)&Vs[nxt][(sr+32)*64 + sc] = vr1;
        }
        if (kt + 1 < qbt) {
            const int kn = (kt+2)*64;
            kr0 = *(const uint4*)(kbase + (size_t)(kn+sr)*HD_ + sj*8);
            kr1 = *(const uint4*)(kbase + (size_t)(kn+sr+32)*HD_ + sj*8);
            vr0 = *(const uint4*)(vbase + (size_t)sr*T_ + kn + sj*8);
            vr1 = *(const uint4*)(vbase + (size_t)(sr+32)*T_ + kn + sj*8);
        }
        if (kt == qbt) {  // causal boundary for state B (last iteration)
            #pragma unroll
            for (int t = 0; t < 4; ++t)
                #pragma unroll
                for (int r = 0; r < 4; ++r)
                    if (kt*64 + t*16 + quad*4 + r > qgB) sB[t][r] = -1e30f;
        }

        float psB = 0.f;
        #pragma unroll
        for (int t = 0; t < 4; ++t) {
            f16x4 pfB = smrow(sB[t], psB);
            const int cv = ((2*t + (quad>>1)) ^ rk7) * 8 + (quad&1)*4;
            #pragma unroll
            for (int dt=0;dt<4;++dt) {
                f16x4 va = *(const f16x4*)&VsC[(dt*16 + q16)*64 + cv];
                oB[dt] = __builtin_amdgcn_mfma_f32_16x16x16f16(va, pfB, oB[dt], 0, 0, 0);
            }
        }
        lB += psB;
        __builtin_amdgcn_s_setprio(0);
        __syncthreads();
        cur ^= 1;
    }

    lA += __shfl_xor(lA, 16); lA += __shfl_xor(lA, 32);
    lB += __shfl_xor(lB, 16); lB += __shfl_xor(lB, 32);
    const float rlA = 1.0f / lA;
    const float rlB = 1.0f / lB;
    unsigned short* opA = Ob + ((size_t)(b*T_ + qgA))*(HQ_*HD_) + h*HD_;
    unsigned short* opB = Ob + ((size_t)(b*T_ + qgB))*(HQ_*HD_) + h*HD_;
    #pragma unroll
    for (int dt = 0; dt < 4; ++dt) {
        uint2 pa, pb;
        pa.x = (unsigned int)f2bf(oA[dt][0]*rlA) | ((unsigned int)f2bf(oA[dt][1]*rlA) << 16);
        pa.y = (unsigned int)f2bf(oA[dt][2]*rlA) | ((unsigned int)f2bf(oA[dt][3]*rlA) << 16);
        pb.x = (unsigned int)f2bf(oB[dt][0]*rlB) | ((unsigned int)f2bf(oB[dt][1]*rlB) << 16);
        pb.y = (unsigned int)f2bf(oB[dt][2]*rlB) | ((unsigned int)f2bf(oB[dt][3]*rlB) << 16);
        *(uint2*)(opA + dt*16 + quad*4) = pa;
        *(uint2*)(opB + dt*16 + quad*4) = pb;
    }
}

// ---------------- Output projection: bf16 MFMA GEMM ----------------
__global__ __launch_bounds__(256) void out_gemm_bf16(
    const unsigned short* __restrict__ Ab, const unsigned short* __restrict__ Wb,
    float* __restrict__ C)
{
    __shared__ unsigned short As[128*32];
    __shared__ unsigned short Bs[128*32];
    const int tid  = threadIdx.x;
    const int ln   = tid & 63;
    const int wv   = tid >> 6;
    const int wm   = (wv >> 1) * 64;
    const int wn   = (wv & 1) * 64;
    const int col  = ln & 15;
    const int quad = ln >> 4;
    const int m0   = blockIdx.y * 128;
    const int n0   = blockIdx.x * 128;

    const unsigned short* aG = Ab + (size_t)(m0 + (tid>>2))*DM_ + (tid&3)*8;
    const unsigned short* bG = Wb + (size_t)(n0 + (tid>>2))*DM_ + (tid&3)*8;
    unsigned short* aL0 = &As[wv*512];
    unsigned short* aL1 = &As[wv*512 + 2048];
    unsigned short* bL0 = &Bs[wv*512];
    unsigned short* bL1 = &Bs[wv*512 + 2048];

    f32x4 acc[4][4];
    #pragma unroll
    for (int i=0;i<4;++i)
        #pragma unroll
        for (int j=0;j<4;++j) { acc[i][j][0]=0.f; acc[i][j][1]=0.f; acc[i][j][2]=0.f; acc[i][j][3]=0.f; }

    for (int k0 = 0; k0 < DM_; k0 += 32) {
        __syncthreads();
        gload16(aG + k0,                  aL0);
        gload16(aG + (size_t)64*DM_ + k0, aL1);
        gload16(bG + k0,                  bL0);
        gload16(bG + (size_t)64*DM_ + k0, bL1);
        __syncthreads();
        bf16x8 af[4], bfr[4];
        #pragma unroll
        for (int i=0;i<4;++i) {
            af[i]  = *(const bf16x8*)&As[(wm + i*16 + col)*32 + quad*8];
            bfr[i] = *(const bf16x8*)&Bs[(wn + i*16 + col)*32 + quad*8];
        }
        #pragma unroll
        for (int i=0;i<4;++i)
            #pragma unroll
            for (int j=0;j<4;++j)
                acc[i][j] = __builtin_amdgcn_mfma_f32_16x16x32_bf16(af[i], bfr[j], acc[i][j], 0, 0, 0);
    }

    #pragma unroll
    for (int i=0;i<4;++i) {
        const int m = m0 + wm + i*16 + quad*4;
        #pragma unroll
        for (int j=0;j<4;++j) {
            const int n = n0 + wn + j*16 + col;
            #pragma unroll
            for (int r=0;r<4;++r)
                C[(size_t)(m + r)*DM_ + n] = acc[i][j][r];
        }
    }
}

extern "C" void kernel_launch(void* const* d_in, const int* in_sizes, int n_in,
                              void* d_out, int out_size, void* d_ws, size_t ws_size,
                              hipStream_t stream) {
    const float* x   = (const float*)d_in[0];
    const int*   pos = (const int*)  d_in[1];
    const float* WQ  = (const float*)d_in[2];
    const float* WK  = (const float*)d_in[3];
    const float* WV  = (const float*)d_in[4];
    const float* WO  = (const float*)d_in[5];
    float* out = (float*)d_out;

    unsigned short* xb  = (unsigned short*)d_ws;
    unsigned short* Wb  = xb  + (size_t)8388608;
    unsigned short* WOb = Wb  + (size_t)6291456;
    unsigned short* Qb  = WOb + (size_t)4194304;
    unsigned short* Kb  = Qb  + (size_t)8388608;
    unsigned short* Vt  = Kb  + (size_t)2097152;
    unsigned short* Ob  = Vt  + (size_t)2097152;

    // 0) fp32 -> bf16 converts, single launch
    convert_all<<<18432, 256, 0, stream>>>(x, WQ, WK, WV, WO, (unsigned short*)d_ws);

    // 1) QKV projection -> Qb/Kb bf16 pre-RoPE, Vt f16 transposed
    dim3 g1(24, 32);
    qkv_gemm_bf16<<<g1, 256, 0, stream>>>(xb, Wb, Qb, Kb, Vt);

    // 2) RoPE in place (Q scaled log2e/8)
    const int pairs = B_*HQ_*T_*(HD_/2) + B_*HKV_*T_*(HD_/2);
    rope_inplace<<<(pairs + 255)/256, 256, 0, stream>>>(Qb, Kb, pos);

    // 3) Causal GQA flash attention (paired Q-tiles, dbuf + pipe-interleaved)
    dim3 g3(16, B_*HQ_);
    attn_mfma<<<g3, 256, 0, stream>>>(Qb, Kb, Vt, Ob);

    // 4) Output projection -> fp32 out
    dim3 g4(16, 32);
    out_gemm_bf16<<<g4, 256, 0, stream>>>(Ob, WOb, out);
}

// Round 2
// 335.309 us; speedup vs baseline: 1.0729x; 1.0070x over previous
//
#include <hip/hip_runtime.h>
#include <hip/hip_bf16.h>

#define B_   2
#define T_   2048
#define DM_  2048
#define HQ_  32
#define HKV_ 8
#define HD_  64

typedef __attribute__((ext_vector_type(8))) short bf16x8;
typedef __attribute__((ext_vector_type(4))) float f32x4;
typedef __fp16 f16x4 __attribute__((ext_vector_type(4)));
typedef __fp16 f16x2 __attribute__((ext_vector_type(2)));

__device__ __forceinline__ unsigned short f2bf(float f) {
    unsigned int u = __float_as_uint(f);
    u = (u + 0x7fffu + ((u >> 16) & 1u)) >> 16;   // RNE
    return (unsigned short)u;
}

__device__ __forceinline__ void gload16(const unsigned short* g, unsigned short* l) {
    __builtin_amdgcn_global_load_lds(
        (const __attribute__((address_space(1))) unsigned int*)g,
        (__attribute__((address_space(3))) unsigned int*)l, 16, 0, 0);
}

// ---------------------------------------------------------------------------
// Workspace (ushort elements, 76 MiB total):
//   xb  : 8388608   (4096,2048)      bf16 x
//   Wb  : 6291456   (3072,2048)      bf16 [WQ;WK;WV]
//   WOb : 4194304   (2048,2048)      bf16 WO
//   Qb  : 8388608   (B,HQ,T,HD)      bf16 Q (RoPE'd in place, scaled log2e/8)
//   Kb  : 2097152   (B,HKV,T,HD)     bf16 K (RoPE'd in place)
//   Vt  : 2097152   (B,HKV,HD,T)     f16 V transposed
//   Ob  : 8388608   (B,T,HQ*HD)      bf16 attention out
// ---------------------------------------------------------------------------

// ---------------- merged fp32 -> bf16 convert (x, WQ, WK, WV, WO) ----------
__global__ __launch_bounds__(256) void convert_all(
    const float* __restrict__ x,  const float* __restrict__ WQ,
    const float* __restrict__ WK, const float* __restrict__ WV,
    const float* __restrict__ WO, unsigned short* __restrict__ ws)
{
    int i = blockIdx.x*256 + threadIdx.x;        // float4 index, total 4718592
    const float* src; unsigned short* dst; int rel;
    if (i < 2097152)      { src = x;  dst = ws;                 rel = i; }
    else if (i < 3145728) { src = WQ; dst = ws + 8388608;       rel = i - 2097152; }
    else if (i < 3407872) { src = WK; dst = ws + 8388608+4194304; rel = i - 3145728; }
    else if (i < 3670016) { src = WV; dst = ws + 8388608+5242880; rel = i - 3407872; }
    else                  { src = WO; dst = ws + 14680064;      rel = i - 3670016; }
    float4 v = *(const float4*)(src + (size_t)rel*4);
    uint2 pk;
    pk.x = (unsigned int)f2bf(v.x) | ((unsigned int)f2bf(v.y) << 16);
    pk.y = (unsigned int)f2bf(v.z) | ((unsigned int)f2bf(v.w) << 16);
    *(uint2*)(dst + (size_t)rel*4) = pk;
}

// ---------------- QKV projection: bf16 MFMA GEMM, 2-phase pipelined --------
// R9 vs R8: (a) LDS double-buffer + prefetch-before-compute, ONE barrier per
// K-step — the global_load_lds drain overlaps the MFMAs instead of sitting
// between two barriers. (b) T2 XOR chunk-swizzle: LDS dest stays LINEAR
// (global_load_lds requirement, rule 21); the GLOBAL source column is
// pre-swizzled with the same involution the reads use:
//   LDS(row, c) holds global chunk  c ^ ((row>>1)&3)
//   read chunk for global quad q at row r:  q ^ ((r>>1)&3) = q ^ ((col>>1)&3)
// This turns the 8-way bank conflict of the 64B-stride row-major tile
// (banks = row*16 mod 32, 16 lanes on 2 banks) into a free 2-way pattern.
__global__ __launch_bounds__(256) void qkv_gemm_bf16(
    const unsigned short* __restrict__ Ab, const unsigned short* __restrict__ Wb,
    unsigned short* __restrict__ Qb, unsigned short* __restrict__ Kb,
    unsigned short* __restrict__ Vt)
{
    __shared__ unsigned short As[2][128*32];
    __shared__ unsigned short Bs[2][128*32];
    const int tid  = threadIdx.x;
    const int ln   = tid & 63;
    const int wv   = tid >> 6;
    const int wm   = (wv >> 1) * 64;
    const int wn   = (wv & 1) * 64;
    const int col  = ln & 15;
    const int quad = ln >> 4;
    const int m0   = blockIdx.y * 128;
    const int n0   = blockIdx.x * 128;

    // pre-swizzled global source column (involution: XOR by (row>>1)&3)
    const int cg = ((tid & 3) ^ ((tid >> 3) & 3)) * 8;
    const unsigned short* aG = Ab + (size_t)(m0 + (tid>>2))*DM_ + cg;
    const unsigned short* bG = Wb + (size_t)(n0 + (tid>>2))*DM_ + cg;
    // swizzled read chunk (lane-constant)
    const int ck = (quad ^ ((col >> 1) & 3)) * 8;

    f32x4 acc[4][4];
    #pragma unroll
    for (int i=0;i<4;++i)
        #pragma unroll
        for (int j=0;j<4;++j) { acc[i][j][0]=0.f; acc[i][j][1]=0.f; acc[i][j][2]=0.f; acc[i][j][3]=0.f; }

    // prologue: stage K-tile 0 into buf 0
    {
        unsigned short* aL = &As[0][wv*512];
        unsigned short* bL = &Bs[0][wv*512];
        gload16(aG,                  aL);
        gload16(aG + (size_t)64*DM_, aL + 2048);
        gload16(bG,                  bL);
        gload16(bG + (size_t)64*DM_, bL + 2048);
    }
    __syncthreads();

    int cur = 0;
    for (int k0 = 0; k0 < DM_; k0 += 32) {
        // issue next-tile staging first; it drains under this tile's compute
        if (k0 + 32 < DM_) {
            unsigned short* aL = &As[cur^1][wv*512];
            unsigned short* bL = &Bs[cur^1][wv*512];
            gload16(aG + k0 + 32,                  aL);
            gload16(aG + (size_t)64*DM_ + k0 + 32, aL + 2048);
            gload16(bG + k0 + 32,                  bL);
            gload16(bG + (size_t)64*DM_ + k0 + 32, bL + 2048);
        }
        bf16x8 af[4], bfr[4];
        #pragma unroll
        for (int i=0;i<4;++i) {
            af[i]  = *(const bf16x8*)&As[cur][(wm + i*16 + col)*32 + ck];
            bfr[i] = *(const bf16x8*)&Bs[cur][(wn + i*16 + col)*32 + ck];
        }
        #pragma unroll
        for (int i=0;i<4;++i)
            #pragma unroll
            for (int j=0;j<4;++j)
                acc[i][j] = __builtin_amdgcn_mfma_f32_16x16x32_bf16(af[i], bfr[j], acc[i][j], 0, 0, 0);
        __syncthreads();   // drains this iter's stage (vmcnt) + read fences
        cur ^= 1;
    }

    const int b  = m0 >> 11;
    const int tb = m0 & 2047;
    #pragma unroll
    for (int j=0;j<4;++j) {
        const int n = n0 + wn + j*16 + col;
        #pragma unroll
        for (int i=0;i<4;++i) {
            const int t = tb + wm + i*16 + quad*4;
            if (n < 2048) {
                #pragma unroll
                for (int r=0;r<4;++r)
                    Qb[(((size_t)(b*HQ_ + (n>>6)))*T_ + t + r)*HD_ + (n&63)] = f2bf(acc[i][j][r]);
            } else if (n < 2560) {
                #pragma unroll
                for (int r=0;r<4;++r)
                    Kb[(((size_t)(b*HKV_ + ((n-2048)>>6)))*T_ + t + r)*HD_ + (n&63)] = f2bf(acc[i][j][r]);
            } else {
                unsigned short* vp = Vt + (((size_t)(b*HKV_ + ((n-2560)>>6)))*HD_ + (n&63))*T_ + t;
                union { f16x2 h; unsigned int u; } c0, c1;
                c0.h = __builtin_amdgcn_cvt_pkrtz(acc[i][j][0], acc[i][j][1]);
                c1.h = __builtin_amdgcn_cvt_pkrtz(acc[i][j][2], acc[i][j][3]);
                *(unsigned int*)(vp)     = c0.u;
                *(unsigned int*)(vp + 2) = c1.u;
            }
        }
    }
}

// ---------------- RoPE in place; Q scaled by log2(e)/8 ----------------
__global__ __launch_bounds__(256) void rope_inplace(
    unsigned short* __restrict__ Qb, unsigned short* __restrict__ Kb,
    const int* __restrict__ pos)
{
    const int NQ = B_*HQ_*T_*(HD_/2);
    const int NK = B_*HKV_*T_*(HD_/2);
    int idx = blockIdx.x*256 + threadIdx.x;
    unsigned short* base; float scale;
    int rem;
    if (idx < NQ) { base = Qb; rem = idx; scale = 0.18033688011112042f; }  // log2(e)/8
    else { rem = idx - NQ; if (rem >= NK) return; base = Kb; scale = 1.0f; }
    const int i  = rem & 31;
    const int t  = (rem >> 5) & (T_ - 1);
    const int bh = rem >> 16;
    size_t off = (((size_t)bh)*T_ + t)*HD_ + (i<<1);
    unsigned int pk = *(unsigned int*)(base + off);
    float x1 = __uint_as_float((pk & 0xffffu) << 16);
    float x2 = __uint_as_float(pk & 0xffff0000u);
    float p = (float)pos[t];
    float inv = exp2f(-13.287712379549449f * ((float)(i<<1)) * (1.0f/64.0f));
    float ang = p * inv;
    float sn, cs;
    sincosf(ang, &sn, &cs);
    float r1 = (x1*cs - x2*sn) * scale;
    float r2 = (x1*sn + x2*cs) * scale;
    unsigned int out = (unsigned int)f2bf(r1) | ((unsigned int)f2bf(r2) << 16);
    *(unsigned int*)(base + off) = out;
}

// ---------------- MFMA flash attention, paired Q-tiles, pipelined ----------
// (unchanged from R8: dbuf LDS, one barrier/tile, branchless phase split,
// SM interleaved under MFMAs, setprio around compute)
__global__ __launch_bounds__(256, 2) void attn_mfma(
    const unsigned short* __restrict__ Qb, const unsigned short* __restrict__ Kb,
    const unsigned short* __restrict__ Vh, unsigned short* __restrict__ Ob)
{
    __shared__ unsigned short Ks[2][64*64];    // bf16 K rows (k), d chunks swizzled
    __shared__ unsigned short Vs[2][64*64];    // f16 V^T rows (d), k chunks swizzled

    const int tid  = threadIdx.x;
    const int lane = tid & 63;
    const int wave = tid >> 6;
    const int q16  = lane & 15;
    const int quad = lane >> 4;
    const int bxi  = blockIdx.x;          // 0..15
    const int bh   = blockIdx.y;
    const int b    = bh >> 5;
    const int h    = bh & 31;
    const int kvh  = h >> 2;
    const int qa   = bxi;                 // 0..15
    const int qbt  = 31 - bxi;            // 16..31 (qa < qbt always)
    const int qgA  = qa *64 + wave*16 + q16;
    const int qgB  = qbt*64 + wave*16 + q16;

    const unsigned short* kbase = Kb + ((size_t)(b*HKV_ + kvh))*T_*HD_;
    const unsigned short* vbase = Vh + ((size_t)(b*HKV_ + kvh))*(size_t)HD_*T_;

    const bf16x8 qA0 = *(const bf16x8*)(Qb + ((size_t)bh*T_ + qgA)*HD_ + quad*8);
    const bf16x8 qA1 = *(const bf16x8*)(Qb + ((size_t)bh*T_ + qgA)*HD_ + 32 + quad*8);
    const bf16x8 qB0 = *(const bf16x8*)(Qb + ((size_t)bh*T_ + qgB)*HD_ + quad*8);
    const bf16x8 qB1 = *(const bf16x8*)(Qb + ((size_t)bh*T_ + qgB)*HD_ + 32 + quad*8);

    f32x4 oA[4], oB[4];
    #pragma unroll
    for (int i=0;i<4;++i) {
        oA[i][0]=0.f; oA[i][1]=0.f; oA[i][2]=0.f; oA[i][3]=0.f;
        oB[i][0]=0.f; oB[i][1]=0.f; oB[i][2]=0.f; oB[i][3]=0.f;
    }
    float lA = 0.f, lB = 0.f;

    const int sr = tid >> 3;              // 0..31
    const int sj = tid & 7;               // 16B chunk
    const int sc = (sj ^ (sr & 7)) * 8;   // (sr+32)&7 == sr&7

    const int rk7 = q16 & 7;
    const int ck0 = (quad ^ rk7) * 8;
    const int ck1 = ((quad + 4) ^ rk7) * 8;

    auto smrow = [&](const f32x4 s, float& ps) -> f16x4 {
        float e0 = exp2f(s[0]), e1 = exp2f(s[1]);
        float e2 = exp2f(s[2]), e3 = exp2f(s[3]);
        ps += (e0+e1) + (e2+e3);
        union { f16x2 h[2]; f16x4 v; } c;
        c.h[0] = __builtin_amdgcn_cvt_pkrtz(e0, e1);
        c.h[1] = __builtin_amdgcn_cvt_pkrtz(e2, e3);
        return c.v;
    };

    uint4 kr0, kr1, vr0, vr1;
    kr0 = *(const uint4*)(kbase + (size_t)sr*HD_ + sj*8);
    kr1 = *(const uint4*)(kbase + (size_t)(sr+32)*HD_ + sj*8);
    vr0 = *(const uint4*)(vbase + (size_t)sr*T_ + sj*8);
    vr1 = *(const uint4*)(vbase + (size_t)(sr+32)*T_ + sj*8);
    *(uint4*)&Ks[0][sr*64 + sc]      = kr0;
    *(uint4*)&Ks[0][(sr+32)*64 + sc] = kr1;
    *(uint4*)&Vs[0][sr*64 + sc]      = vr0;
    *(uint4*)&Vs[0][(sr+32)*64 + sc] = vr1;
    kr0 = *(const uint4*)(kbase + (size_t)(64+sr)*HD_ + sj*8);
    kr1 = *(const uint4*)(kbase + (size_t)(64+sr+32)*HD_ + sj*8);
    vr0 = *(const uint4*)(vbase + (size_t)sr*T_ + 64 + sj*8);
    vr1 = *(const uint4*)(vbase + (size_t)(sr+32)*T_ + 64 + sj*8);
    __syncthreads();

    int cur = 0;

    // ---- phase 1: both Q-states (kt <= qa < qbt), branchless body ----------
    for (int kt = 0; kt <= qa; ++kt) {
        const unsigned short* KsC = Ks[cur];
        const unsigned short* VsC = Vs[cur];
        const int nxt = cur ^ 1;

        f32x4 sB[4], sA[4];
        #pragma unroll
        for (int t=0;t<4;++t) {
            sB[t][0]=0.f; sB[t][1]=0.f; sB[t][2]=0.f; sB[t][3]=0.f;
            sA[t][0]=0.f; sA[t][1]=0.f; sA[t][2]=0.f; sA[t][3]=0.f;
        }
        f16x4 pfB[4];
        float psB = 0.f, psA = 0.f;

        __builtin_amdgcn_s_setprio(1);
        #pragma unroll
        for (int t = 0; t < 4; ++t) {
            const int rk = (t*16 + q16) * 64;
            bf16x8 a0 = *(const bf16x8*)&KsC[rk + ck0];
            bf16x8 a1 = *(const bf16x8*)&KsC[rk + ck1];
            sB[t] = __builtin_amdgcn_mfma_f32_16x16x32_bf16(a0, qB0, sB[t], 0, 0, 0);
            sB[t] = __builtin_amdgcn_mfma_f32_16x16x32_bf16(a1, qB1, sB[t], 0, 0, 0);
            sA[t] = __builtin_amdgcn_mfma_f32_16x16x32_bf16(a0, qA0, sA[t], 0, 0, 0);
            sA[t] = __builtin_amdgcn_mfma_f32_16x16x32_bf16(a1, qA1, sA[t], 0, 0, 0);
            if (t > 0) pfB[t-1] = smrow(sB[t-1], psB);
        }
        *(uint4*)&Ks[nxt][sr*64 + sc]      = kr0;
        *(uint4*)&Ks[nxt][(sr+32)*64 + sc] = kr1;
        *(uint4*)&Vs[nxt][sr*64 + sc]      = vr0;
        *(uint4*)&Vs[nxt][(sr+32)*64 + sc] = vr1;
        if (kt + 1 < qbt) {
            const int kn = (kt+2)*64;
            kr0 = *(const uint4*)(kbase + (size_t)(kn+sr)*HD_ + sj*8);
            kr1 = *(const uint4*)(kbase + (size_t)(kn+sr+32)*HD_ + sj*8);
            vr0 = *(const uint4*)(vbase + (size_t)sr*T_ + kn + sj*8);
            vr1 = *(const uint4*)(vbase + (size_t)(sr+32)*T_ + kn + sj*8);
        }
        pfB[3] = smrow(sB[3], psB);
        lB += psB;

        if (kt == qa) {
            #pragma unroll
            for (int t = 0; t < 4; ++t)
                #pragma unroll
                for (int r = 0; r < 4; ++r)
                    if (kt*64 + t*16 + quad*4 + r > qgA) sA[t][r] = -1e30f;
        }

        #pragma unroll
        for (int t = 0; t < 4; ++t) {
            const int cv = ((2*t + (quad>>1)) ^ rk7) * 8 + (quad&1)*4;
            f16x4 va[4];
            #pragma unroll
            for (int dt=0;dt<4;++dt)
                va[dt] = *(const f16x4*)&VsC[(dt*16 + q16)*64 + cv];
            #pragma unroll
            for (int dt=0;dt<4;++dt)
                oB[dt] = __builtin_amdgcn_mfma_f32_16x16x16f16(va[dt], pfB[t], oB[dt], 0, 0, 0);
            f16x4 pfA = smrow(sA[t], psA);
            #pragma unroll
            for (int dt=0;dt<4;++dt)
                oA[dt] = __builtin_amdgcn_mfma_f32_16x16x16f16(va[dt], pfA, oA[dt], 0, 0, 0);
        }
        lA += psA;
        __builtin_amdgcn_s_setprio(0);
        __syncthreads();
        cur ^= 1;
    }

    // ---- phase 2: state B only (qa < kt <= qbt) ----------------------------
    for (int kt = qa+1; kt <= qbt; ++kt) {
        const unsigned short* KsC = Ks[cur];
        const unsigned short* VsC = Vs[cur];
        const int nxt = cur ^ 1;

        f32x4 sB[4];
        #pragma unroll
        for (int t=0;t<4;++t) { sB[t][0]=0.f; sB[t][1]=0.f; sB[t][2]=0.f; sB[t][3]=0.f; }

        __builtin_amdgcn_s_setprio(1);
        #pragma unroll
        for (int t = 0; t < 4; ++t) {
            const int rk = (t*16 + q16) * 64;
            bf16x8 a0 = *(const bf16x8*)&KsC[rk + ck0];
            bf16x8 a1 = *(const bf16x8*)&KsC[rk + ck1];
            sB[t] = __builtin_amdgcn_mfma_f32_16x16x32_bf16(a0, qB0, sB[t], 0, 0, 0);
            sB[t] = __builtin_amdgcn_mfma_f32_16x16x32_bf16(a1, qB1, sB[t], 0, 0, 0);
        }
        if (kt < qbt) {
            *(uint4*)&Ks[nxt][sr*64 + sc]      = kr0;
            *(uint4*)&Ks[nxt][(sr+32)*64 + sc] = kr1;
            *(uint4*)&Vs[nxt][sr*64 + sc]      = vr0;
            *(uint4*)&Vs[nxt][(sr+32)*64 + sc] = vr1;
        }
        if (kt + 1 < qbt) {
            const int kn = (kt+2)*64;
            kr0 = *(const uint4*)(kbase + (size_t)(kn+sr)*HD_ + sj*8);
            kr1 = *(const uint4*)(kbase + (size_t)(kn+sr+32)*HD_ + sj*8);
            vr0 = *(const uint4*)(vbase + (size_t)sr*T_ + kn + sj*8);
            vr1 = *(const uint4*)(vbase + (size_t)(sr+32)*T_ + kn + sj*8);
        }
        if (kt == qbt) {
            #pragma unroll
            for (int t = 0; t < 4; ++t)
                #pragma unroll
                for (int r = 0; r < 4; ++r)
                    if (kt*64 + t*16 + quad*4 + r > qgB) sB[t][r] = -1e30f;
        }

        float psB = 0.f;
        #pragma unroll
        for (int t = 0; t < 4; ++t) {
            f16x4 pfB = smrow(sB[t], psB);
            const int cv = ((2*t + (quad>>1)) ^ rk7) * 8 + (quad&1)*4;
            #pragma unroll
            for (int dt=0;dt<4;++dt) {
                f16x4 va = *(const f16x4*)&VsC[(dt*16 + q16)*64 + cv];
                oB[dt] = __builtin_amdgcn_mfma_f32_16x16x16f16(va, pfB, oB[dt], 0, 0, 0);
            }
        }
        lB += psB;
        __builtin_amdgcn_s_setprio(0);
        __syncthreads();
        cur ^= 1;
    }

    lA += __shfl_xor(lA, 16); lA += __shfl_xor(lA, 32);
    lB += __shfl_xor(lB, 16); lB += __shfl_xor(lB, 32);
    const float rlA = 1.0f / lA;
    const float rlB = 1.0f / lB;
    unsigned short* opA = Ob + ((size_t)(b*T_ + qgA))*(HQ_*HD_) + h*HD_;
    unsigned short* opB = Ob + ((size_t)(b*T_ + qgB))*(HQ_*HD_) + h*HD_;
    #pragma unroll
    for (int dt = 0; dt < 4; ++dt) {
        uint2 pa, pb;
        pa.x = (unsigned int)f2bf(oA[dt][0]*rlA) | ((unsigned int)f2bf(oA[dt][1]*rlA) << 16);
        pa.y = (unsigned int)f2bf(oA[dt][2]*rlA) | ((unsigned int)f2bf(oA[dt][3]*rlA) << 16);
        pb.x = (unsigned int)f2bf(oB[dt][0]*rlB) | ((unsigned int)f2bf(oB[dt][1]*rlB) << 16);
        pb.y = (unsigned int)f2bf(oB[dt][2]*rlB) | ((unsigned int)f2bf(oB[dt][3]*rlB) << 16);
        *(uint2*)(opA + dt*16 + quad*4) = pa;
        *(uint2*)(opB + dt*16 + quad*4) = pb;
    }
}

// ---------------- Output projection: bf16 MFMA GEMM, 2-phase pipelined -----
__global__ __launch_bounds__(256) void out_gemm_bf16(
    const unsigned short* __restrict__ Ab, const unsigned short* __restrict__ Wb,
    float* __restrict__ C)
{
    __shared__ unsigned short As[2][128*32];
    __shared__ unsigned short Bs[2][128*32];
    const int tid  = threadIdx.x;
    const int ln   = tid & 63;
    const int wv   = tid >> 6;
    const int wm   = (wv >> 1) * 64;
    const int wn   = (wv & 1) * 64;
    const int col  = ln & 15;
    const int quad = ln >> 4;
    const int m0   = blockIdx.y * 128;
    const int n0   = blockIdx.x * 128;

    const int cg = ((tid & 3) ^ ((tid >> 3) & 3)) * 8;
    const unsigned short* aG = Ab + (size_t)(m0 + (tid>>2))*DM_ + cg;
    const unsigned short* bG = Wb + (size_t)(n0 + (tid>>2))*DM_ + cg;
    const int ck = (quad ^ ((col >> 1) & 3)) * 8;

    f32x4 acc[4][4];
    #pragma unroll
    for (int i=0;i<4;++i)
        #pragma unroll
        for (int j=0;j<4;++j) { acc[i][j][0]=0.f; acc[i][j][1]=0.f; acc[i][j][2]=0.f; acc[i][j][3]=0.f; }

    {
        unsigned short* aL = &As[0][wv*512];
        unsigned short* bL = &Bs[0][wv*512];
        gload16(aG,                  aL);
        gload16(aG + (size_t)64*DM_, aL + 2048);
        gload16(bG,                  bL);
        gload16(bG + (size_t)64*DM_, bL + 2048);
    }
    __syncthreads();

    int cur = 0;
    for (int k0 = 0; k0 < DM_; k0 += 32) {
        if (k0 + 32 < DM_) {
            unsigned short* aL = &As[cur^1][wv*512];
            unsigned short* bL = &Bs[cur^1][wv*512];
            gload16(aG + k0 + 32,                  aL);
            gload16(aG + (size_t)64*DM_ + k0 + 32, aL + 2048);
            gload16(bG + k0 + 32,                  bL);
            gload16(bG + (size_t)64*DM_ + k0 + 32, bL + 2048);
        }
        bf16x8 af[4], bfr[4];
        #pragma unroll
        for (int i=0;i<4;++i) {
            af[i]  = *(const bf16x8*)&As[cur][(wm + i*16 + col)*32 + ck];
            bfr[i] = *(const bf16x8*)&Bs[cur][(wn + i*16 + col)*32 + ck];
        }
        #pragma unroll
        for (int i=0;i<4;++i)
            #pragma unroll
            for (int j=0;j<4;++j)
                acc[i][j] = __builtin_amdgcn_mfma_f32_16x16x32_bf16(af[i], bfr[j], acc[i][j], 0, 0, 0);
        __syncthreads();
        cur ^= 1;
    }

    #pragma unroll
    for (int i=0;i<4;++i) {
        const int m = m0 + wm + i*16 + quad*4;
        #pragma unroll
        for (int j=0;j<4;++j) {
            const int n = n0 + wn + j*16 + col;
            #pragma unroll
            for (int r=0;r<4;++r)
                C[(size_t)(m + r)*DM_ + n] = acc[i][j][r];
        }
    }
}

extern "C" void kernel_launch(void* const* d_in, const int* in_sizes, int n_in,
                              void* d_out, int out_size, void* d_ws, size_t ws_size,
                              hipStream_t stream) {
    const float* x   = (const float*)d_in[0];
    const int*   pos = (const int*)  d_in[1];
    const float* WQ  = (const float*)d_in[2];
    const float* WK  = (const float*)d_in[3];
    const float* WV  = (const float*)d_in[4];
    const float* WO  = (const float*)d_in[5];
    float* out = (float*)d_out;

    unsigned short* xb  = (unsigned short*)d_ws;
    unsigned short* Wb  = xb  + (size_t)8388608;
    unsigned short* WOb = Wb  + (size_t)6291456;
    unsigned short* Qb  = WOb + (size_t)4194304;
    unsigned short* Kb  = Qb  + (size_t)8388608;
    unsigned short* Vt  = Kb  + (size_t)2097152;
    unsigned short* Ob  = Vt  + (size_t)2097152;

    // 0) fp32 -> bf16 converts, single launch
    convert_all<<<18432, 256, 0, stream>>>(x, WQ, WK, WV, WO, (unsigned short*)d_ws);

    // 1) QKV projection -> Qb/Kb bf16 pre-RoPE, Vt f16 transposed
    dim3 g1(24, 32);
    qkv_gemm_bf16<<<g1, 256, 0, stream>>>(xb, Wb, Qb, Kb, Vt);

    // 2) RoPE in place (Q scaled log2e/8)
    const int pairs = B_*HQ_*T_*(HD_/2) + B_*HKV_*T_*(HD_/2);
    rope_inplace<<<(pairs + 255)/256, 256, 0, stream>>>(Qb, Kb, pos);

    // 3) Causal GQA flash attention (paired Q-tiles, dbuf + pipe-interleaved)
    dim3 g3(16, B_*HQ_);
    attn_mfma<<<g3, 256, 0, stream>>>(Qb, Kb, Vt, Ob);

    // 4) Output projection -> fp32 out
    dim3 g4(16, 32);
    out_gemm_bf16<<<g4, 256, 0, stream>>>(Ob, WOb, out);
}

// Round 3
// 333.067 us; speedup vs baseline: 1.0801x; 1.0067x over previous
//
#include <hip/hip_runtime.h>
#include <hip/hip_bf16.h>

#define B_   2
#define T_   2048
#define DM_  2048
#define HQ_  32
#define HKV_ 8
#define HD_  64

typedef __attribute__((ext_vector_type(8))) short bf16x8;
typedef __attribute__((ext_vector_type(4))) float f32x4;
typedef __fp16 f16x4 __attribute__((ext_vector_type(4)));
typedef __fp16 f16x2 __attribute__((ext_vector_type(2)));

__device__ __forceinline__ unsigned short f2bf(float f) {
    unsigned int u = __float_as_uint(f);
    u = (u + 0x7fffu + ((u >> 16) & 1u)) >> 16;   // RNE
    return (unsigned short)u;
}

__device__ __forceinline__ void gload16(const unsigned short* g, unsigned short* l) {
    __builtin_amdgcn_global_load_lds(
        (const __attribute__((address_space(1))) unsigned int*)g,
        (__attribute__((address_space(3))) unsigned int*)l, 16, 0, 0);
}

// ---------------------------------------------------------------------------
// Workspace (ushort elements, 76 MiB total):
//   xb  : 8388608   (4096,2048)      bf16 x
//   Wb  : 6291456   (3072,2048)      bf16 [WQ;WK;WV]
//   WOb : 4194304   (2048,2048)      bf16 WO
//   Qb  : 8388608   (B,HQ,T,HD)      bf16 Q (RoPE'd in place, scaled log2e/8)
//   Kb  : 2097152   (B,HKV,T,HD)     bf16 K (RoPE'd in place)
//   Vt  : 2097152   (B,HKV,HD,T)     f16 V transposed
//   Ob  : 8388608   (B,T,HQ*HD)      bf16 attention out
// ---------------------------------------------------------------------------

// ---------------- merged fp32 -> bf16 convert (x, WQ, WK, WV, WO) ----------
__global__ __launch_bounds__(256) void convert_all(
    const float* __restrict__ x,  const float* __restrict__ WQ,
    const float* __restrict__ WK, const float* __restrict__ WV,
    const float* __restrict__ WO, unsigned short* __restrict__ ws)
{
    int i = blockIdx.x*256 + threadIdx.x;        // float4 index, total 4718592
    const float* src; unsigned short* dst; int rel;
    if (i < 2097152)      { src = x;  dst = ws;                 rel = i; }
    else if (i < 3145728) { src = WQ; dst = ws + 8388608;       rel = i - 2097152; }
    else if (i < 3407872) { src = WK; dst = ws + 8388608+4194304; rel = i - 3145728; }
    else if (i < 3670016) { src = WV; dst = ws + 8388608+5242880; rel = i - 3407872; }
    else                  { src = WO; dst = ws + 14680064;      rel = i - 3670016; }
    float4 v = *(const float4*)(src + (size_t)rel*4);
    uint2 pk;
    pk.x = (unsigned int)f2bf(v.x) | ((unsigned int)f2bf(v.y) << 16);
    pk.y = (unsigned int)f2bf(v.z) | ((unsigned int)f2bf(v.w) << 16);
    *(uint2*)(dst + (size_t)rel*4) = pk;
}

// ---------------- QKV projection: bf16 MFMA GEMM, tri-buffered -------------
// R10 vs R9: R9's dbuf+prefetch was still latency-bound: __syncthreads drains
// vmcnt(0), so each K-step serialized (staging latency - compute) at the
// barrier (MfmaUtil stuck at 21%, nothing saturated). Now:
//  * T4 counted vmcnt: 3 LDS buffers, prologue stages tiles 0,1; per iter
//      s_waitcnt vmcnt(4) -> s_barrier -> issue stage(t+2) -> ds_read+MFMA
//    Tile t's loads get 2 full iterations of latency cover; the barrier no
//    longer drains the in-flight prefetch. Ledger: stage(t+2) writes
//    buf[(t+2)%3] = buf[(t-1)%3], last read in iter t-1 (before barrier(t))
//    -> no WAR race. vmcnt(4) at iter-top = stage(t) done (stage(t+1) still
//    outstanding); barrier makes it all-waves. Tail: vmcnt(0) on last iter.
//  * T1 XCD swizzle: 768 blocks = 8 XCDs x 96 contiguous tiles (bijective,
//    nwg%8==0) -> A-panels stop being replicated into all 8 private L2s.
//  * T2 read-chunk swizzle kept from R9 (conflicts = 0).
__global__ __launch_bounds__(256) void qkv_gemm_bf16(
    const unsigned short* __restrict__ Ab, const unsigned short* __restrict__ Wb,
    unsigned short* __restrict__ Qb, unsigned short* __restrict__ Kb,
    unsigned short* __restrict__ Vt)
{
    __shared__ unsigned short As[3][128*32];
    __shared__ unsigned short Bs[3][128*32];
    const int tid  = threadIdx.x;
    const int ln   = tid & 63;
    const int wv   = tid >> 6;
    const int wm   = (wv >> 1) * 64;
    const int wn   = (wv & 1) * 64;
    const int col  = ln & 15;
    const int quad = ln >> 4;

    // XCD-aware bijective block swizzle: 768 = 8 * 96
    const int bid = blockIdx.x;
    const int swz = (bid & 7) * 96 + (bid >> 3);
    const int n0  = (swz % 24) * 128;
    const int m0  = (swz / 24) * 128;

    // pre-swizzled global source column (involution: XOR by (row>>1)&3)
    const int cg = ((tid & 3) ^ ((tid >> 3) & 3)) * 8;
    const unsigned short* aG = Ab + (size_t)(m0 + (tid>>2))*DM_ + cg;
    const unsigned short* bG = Wb + (size_t)(n0 + (tid>>2))*DM_ + cg;
    // swizzled read chunk (lane-constant)
    const int ck = (quad ^ ((col >> 1) & 3)) * 8;

    f32x4 acc[4][4];
    #pragma unroll
    for (int i=0;i<4;++i)
        #pragma unroll
        for (int j=0;j<4;++j) { acc[i][j][0]=0.f; acc[i][j][1]=0.f; acc[i][j][2]=0.f; acc[i][j][3]=0.f; }

    auto stage = [&](int buf, int k0) {
        unsigned short* aL = &As[buf][wv*512];
        unsigned short* bL = &Bs[buf][wv*512];
        gload16(aG + k0,                  aL);
        gload16(aG + (size_t)64*DM_ + k0, aL + 2048);
        gload16(bG + k0,                  bL);
        gload16(bG + (size_t)64*DM_ + k0, bL + 2048);
    };

    // prologue: tiles 0 and 1 in flight (8 outstanding loads per wave)
    stage(0, 0);
    stage(1, 32);

    int kt = 0;
    for (int k0 = 0; k0 < DM_; k0 += 32, ++kt) {
        if (k0 + 32 < DM_) {
            asm volatile("s_waitcnt vmcnt(4)" ::: "memory");   // tile kt landed
        } else {
            asm volatile("s_waitcnt vmcnt(0)" ::: "memory");   // tail drain
        }
        __builtin_amdgcn_s_barrier();
        if (k0 + 64 < DM_) stage((kt+2)%3, k0 + 64);           // depth-2 prefetch
        const unsigned short* Ac = As[kt%3];
        const unsigned short* Bc = Bs[kt%3];
        bf16x8 af[4], bfr[4];
        #pragma unroll
        for (int i=0;i<4;++i) {
            af[i]  = *(const bf16x8*)&Ac[(wm + i*16 + col)*32 + ck];
            bfr[i] = *(const bf16x8*)&Bc[(wn + i*16 + col)*32 + ck];
        }
        #pragma unroll
        for (int i=0;i<4;++i)
            #pragma unroll
            for (int j=0;j<4;++j)
                acc[i][j] = __builtin_amdgcn_mfma_f32_16x16x32_bf16(af[i], bfr[j], acc[i][j], 0, 0, 0);
    }

    const int b  = m0 >> 11;
    const int tb = m0 & 2047;
    #pragma unroll
    for (int j=0;j<4;++j) {
        const int n = n0 + wn + j*16 + col;
        #pragma unroll
        for (int i=0;i<4;++i) {
            const int t = tb + wm + i*16 + quad*4;
            if (n < 2048) {
                #pragma unroll
                for (int r=0;r<4;++r)
                    Qb[(((size_t)(b*HQ_ + (n>>6)))*T_ + t + r)*HD_ + (n&63)] = f2bf(acc[i][j][r]);
            } else if (n < 2560) {
                #pragma unroll
                for (int r=0;r<4;++r)
                    Kb[(((size_t)(b*HKV_ + ((n-2048)>>6)))*T_ + t + r)*HD_ + (n&63)] = f2bf(acc[i][j][r]);
            } else {
                unsigned short* vp = Vt + (((size_t)(b*HKV_ + ((n-2560)>>6)))*HD_ + (n&63))*T_ + t;
                union { f16x2 h; unsigned int u; } c0, c1;
                c0.h = __builtin_amdgcn_cvt_pkrtz(acc[i][j][0], acc[i][j][1]);
                c1.h = __builtin_amdgcn_cvt_pkrtz(acc[i][j][2], acc[i][j][3]);
                *(unsigned int*)(vp)     = c0.u;
                *(unsigned int*)(vp + 2) = c1.u;
            }
        }
    }
}

// ---------------- RoPE in place; Q scaled by log2(e)/8 ----------------
__global__ __launch_bounds__(256) void rope_inplace(
    unsigned short* __restrict__ Qb, unsigned short* __restrict__ Kb,
    const int* __restrict__ pos)
{
    const int NQ = B_*HQ_*T_*(HD_/2);
    const int NK = B_*HKV_*T_*(HD_/2);
    int idx = blockIdx.x*256 + threadIdx.x;
    unsigned short* base; float scale;
    int rem;
    if (idx < NQ) { base = Qb; rem = idx; scale = 0.18033688011112042f; }  // log2(e)/8
    else { rem = idx - NQ; if (rem >= NK) return; base = Kb; scale = 1.0f; }
    const int i  = rem & 31;
    const int t  = (rem >> 5) & (T_ - 1);
    const int bh = rem >> 16;
    size_t off = (((size_t)bh)*T_ + t)*HD_ + (i<<1);
    unsigned int pk = *(unsigned int*)(base + off);
    float x1 = __uint_as_float((pk & 0xffffu) << 16);
    float x2 = __uint_as_float(pk & 0xffff0000u);
    float p = (float)pos[t];
    float inv = exp2f(-13.287712379549449f * ((float)(i<<1)) * (1.0f/64.0f));
    float ang = p * inv;
    float sn, cs;
    sincosf(ang, &sn, &cs);
    float r1 = (x1*cs - x2*sn) * scale;
    float r2 = (x1*sn + x2*cs) * scale;
    unsigned int out = (unsigned int)f2bf(r1) | ((unsigned int)f2bf(r2) << 16);
    *(unsigned int*)(base + off) = out;
}

// ---------------- MFMA flash attention, paired Q-tiles, pipelined ----------
// (unchanged from R8/R9)
__global__ __launch_bounds__(256, 2) void attn_mfma(
    const unsigned short* __restrict__ Qb, const unsigned short* __restrict__ Kb,
    const unsigned short* __restrict__ Vh, unsigned short* __restrict__ Ob)
{
    __shared__ unsigned short Ks[2][64*64];    // bf16 K rows (k), d chunks swizzled
    __shared__ unsigned short Vs[2][64*64];    // f16 V^T rows (d), k chunks swizzled

    const int tid  = threadIdx.x;
    const int lane = tid & 63;
    const int wave = tid >> 6;
    const int q16  = lane & 15;
    const int quad = lane >> 4;
    const int bxi  = blockIdx.x;          // 0..15
    const int bh   = blockIdx.y;
    const int b    = bh >> 5;
    const int h    = bh & 31;
    const int kvh  = h >> 2;
    const int qa   = bxi;                 // 0..15
    const int qbt  = 31 - bxi;            // 16..31 (qa < qbt always)
    const int qgA  = qa *64 + wave*16 + q16;
    const int qgB  = qbt*64 + wave*16 + q16;

    const unsigned short* kbase = Kb + ((size_t)(b*HKV_ + kvh))*T_*HD_;
    const unsigned short* vbase = Vh + ((size_t)(b*HKV_ + kvh))*(size_t)HD_*T_;

    const bf16x8 qA0 = *(const bf16x8*)(Qb + ((size_t)bh*T_ + qgA)*HD_ + quad*8);
    const bf16x8 qA1 = *(const bf16x8*)(Qb + ((size_t)bh*T_ + qgA)*HD_ + 32 + quad*8);
    const bf16x8 qB0 = *(const bf16x8*)(Qb + ((size_t)bh*T_ + qgB)*HD_ + quad*8);
    const bf16x8 qB1 = *(const bf16x8*)(Qb + ((size_t)bh*T_ + qgB)*HD_ + 32 + quad*8);

    f32x4 oA[4], oB[4];
    #pragma unroll
    for (int i=0;i<4;++i) {
        oA[i][0]=0.f; oA[i][1]=0.f; oA[i][2]=0.f; oA[i][3]=0.f;
        oB[i][0]=0.f; oB[i][1]=0.f; oB[i][2]=0.f; oB[i][3]=0.f;
    }
    float lA = 0.f, lB = 0.f;

    const int sr = tid >> 3;              // 0..31
    const int sj = tid & 7;               // 16B chunk
    const int sc = (sj ^ (sr & 7)) * 8;   // (sr+32)&7 == sr&7

    const int rk7 = q16 & 7;
    const int ck0 = (quad ^ rk7) * 8;
    const int ck1 = ((quad + 4) ^ rk7) * 8;

    auto smrow = [&](const f32x4 s, float& ps) -> f16x4 {
        float e0 = exp2f(s[0]), e1 = exp2f(s[1]);
        float e2 = exp2f(s[2]), e3 = exp2f(s[3]);
        ps += (e0+e1) + (e2+e3);
        union { f16x2 h[2]; f16x4 v; } c;
        c.h[0] = __builtin_amdgcn_cvt_pkrtz(e0, e1);
        c.h[1] = __builtin_amdgcn_cvt_pkrtz(e2, e3);
        return c.v;
    };

    uint4 kr0, kr1, vr0, vr1;
    kr0 = *(const uint4*)(kbase + (size_t)sr*HD_ + sj*8);
    kr1 = *(const uint4*)(kbase + (size_t)(sr+32)*HD_ + sj*8);
    vr0 = *(const uint4*)(vbase + (size_t)sr*T_ + sj*8);
    vr1 = *(const uint4*)(vbase + (size_t)(sr+32)*T_ + sj*8);
    *(uint4*)&Ks[0][sr*64 + sc]      = kr0;
    *(uint4*)&Ks[0][(sr+32)*64 + sc] = kr1;
    *(uint4*)&Vs[0][sr*64 + sc]      = vr0;
    *(uint4*)&Vs[0][(sr+32)*64 + sc] = vr1;
    kr0 = *(const uint4*)(kbase + (size_t)(64+sr)*HD_ + sj*8);
    kr1 = *(const uint4*)(kbase + (size_t)(64+sr+32)*HD_ + sj*8);
    vr0 = *(const uint4*)(vbase + (size_t)sr*T_ + 64 + sj*8);
    vr1 = *(const uint4*)(vbase + (size_t)(sr+32)*T_ + 64 + sj*8);
    __syncthreads();

    int cur = 0;

    // ---- phase 1: both Q-states (kt <= qa < qbt), branchless body ----------
    for (int kt = 0; kt <= qa; ++kt) {
        const unsigned short* KsC = Ks[cur];
        const unsigned short* VsC = Vs[cur];
        const int nxt = cur ^ 1;

        f32x4 sB[4], sA[4];
        #pragma unroll
        for (int t=0;t<4;++t) {
            sB[t][0]=0.f; sB[t][1]=0.f; sB[t][2]=0.f; sB[t][3]=0.f;
            sA[t][0]=0.f; sA[t][1]=0.f; sA[t][2]=0.f; sA[t][3]=0.f;
        }
        f16x4 pfB[4];
        float psB = 0.f, psA = 0.f;

        __builtin_amdgcn_s_setprio(1);
        #pragma unroll
        for (int t = 0; t < 4; ++t) {
            const int rk = (t*16 + q16) * 64;
            bf16x8 a0 = *(const bf16x8*)&KsC[rk + ck0];
            bf16x8 a1 = *(const bf16x8*)&KsC[rk + ck1];
            sB[t] = __builtin_amdgcn_mfma_f32_16x16x32_bf16(a0, qB0, sB[t], 0, 0, 0);
            sB[t] = __builtin_amdgcn_mfma_f32_16x16x32_bf16(a1, qB1, sB[t], 0, 0, 0);
            sA[t] = __builtin_amdgcn_mfma_f32_16x16x32_bf16(a0, qA0, sA[t], 0, 0, 0);
            sA[t] = __builtin_amdgcn_mfma_f32_16x16x32_bf16(a1, qA1, sA[t], 0, 0, 0);
            if (t > 0) pfB[t-1] = smrow(sB[t-1], psB);
        }
        *(uint4*)&Ks[nxt][sr*64 + sc]      = kr0;
        *(uint4*)&Ks[nxt][(sr+32)*64 + sc] = kr1;
        *(uint4*)&Vs[nxt][sr*64 + sc]      = vr0;
        *(uint4*)&Vs[nxt][(sr+32)*64 + sc] = vr1;
        if (kt + 1 < qbt) {
            const int kn = (kt+2)*64;
            kr0 = *(const uint4*)(kbase + (size_t)(kn+sr)*HD_ + sj*8);
            kr1 = *(const uint4*)(kbase + (size_t)(kn+sr+32)*HD_ + sj*8);
            vr0 = *(const uint4*)(vbase + (size_t)sr*T_ + kn + sj*8);
            vr1 = *(const uint4*)(vbase + (size_t)(sr+32)*T_ + kn + sj*8);
        }
        pfB[3] = smrow(sB[3], psB);
        lB += psB;

        if (kt == qa) {
            #pragma unroll
            for (int t = 0; t < 4; ++t)
                #pragma unroll
                for (int r = 0; r < 4; ++r)
                    if (kt*64 + t*16 + quad*4 + r > qgA) sA[t][r] = -1e30f;
        }

        #pragma unroll
        for (int t = 0; t < 4; ++t) {
            const int cv = ((2*t + (quad>>1)) ^ rk7) * 8 + (quad&1)*4;
            f16x4 va[4];
            #pragma unroll
            for (int dt=0;dt<4;++dt)
                va[dt] = *(const f16x4*)&VsC[(dt*16 + q16)*64 + cv];
            #pragma unroll
            for (int dt=0;dt<4;++dt)
                oB[dt] = __builtin_amdgcn_mfma_f32_16x16x16f16(va[dt], pfB[t], oB[dt], 0, 0, 0);
            f16x4 pfA = smrow(sA[t], psA);
            #pragma unroll
            for (int dt=0;dt<4;++dt)
                oA[dt] = __builtin_amdgcn_mfma_f32_16x16x16f16(va[dt], pfA, oA[dt], 0, 0, 0);
        }
        lA += psA;
        __builtin_amdgcn_s_setprio(0);
        __syncthreads();
        cur ^= 1;
    }

    // ---- phase 2: state B only (qa < kt <= qbt) ----------------------------
    for (int kt = qa+1; kt <= qbt; ++kt) {
        const unsigned short* KsC = Ks[cur];
        const unsigned short* VsC = Vs[cur];
        const int nxt = cur ^ 1;

        f32x4 sB[4];
        #pragma unroll
        for (int t=0;t<4;++t) { sB[t][0]=0.f; sB[t][1]=0.f; sB[t][2]=0.f; sB[t][3]=0.f; }

        __builtin_amdgcn_s_setprio(1);
        #pragma unroll
        for (int t = 0; t < 4; ++t) {
            const int rk = (t*16 + q16) * 64;
            bf16x8 a0 = *(const bf16x8*)&KsC[rk + ck0];
            bf16x8 a1 = *(const bf16x8*)&KsC[rk + ck1];
            sB[t] = __builtin_amdgcn_mfma_f32_16x16x32_bf16(a0, qB0, sB[t], 0, 0, 0);
            sB[t] = __builtin_amdgcn_mfma_f32_16x16x32_bf16(a1, qB1, sB[t], 0, 0, 0);
        }
        if (kt < qbt) {
            *(uint4*)&Ks[nxt][sr*64 + sc]      = kr0;
            *(uint4*)&Ks[nxt][(sr+32)*64 + sc] = kr1;
            *(uint4*)&Vs[nxt][sr*64 + sc]      = vr0;
            *(uint4*)&Vs[nxt][(sr+32)*64 + sc] = vr1;
        }
        if (kt + 1 < qbt) {
            const int kn = (kt+2)*64;
            kr0 = *(const uint4*)(kbase + (size_t)(kn+sr)*HD_ + sj*8);
            kr1 = *(const uint4*)(kbase + (size_t)(kn+sr+32)*HD_ + sj*8);
            vr0 = *(const uint4*)(vbase + (size_t)sr*T_ + kn + sj*8);
            vr1 = *(const uint4*)(vbase + (size_t)(sr+32)*T_ + kn + sj*8);
        }
        if (kt == qbt) {
            #pragma unroll
            for (int t = 0; t < 4; ++t)
                #pragma unroll
                for (int r = 0; r < 4; ++r)
                    if (kt*64 + t*16 + quad*4 + r > qgB) sB[t][r] = -1e30f;
        }

        float psB = 0.f;
        #pragma unroll
        for (int t = 0; t < 4; ++t) {
            f16x4 pfB = smrow(sB[t], psB);
            const int cv = ((2*t + (quad>>1)) ^ rk7) * 8 + (quad&1)*4;
            #pragma unroll
            for (int dt=0;dt<4;++dt) {
                f16x4 va = *(const f16x4*)&VsC[(dt*16 + q16)*64 + cv];
                oB[dt] = __builtin_amdgcn_mfma_f32_16x16x16f16(va, pfB, oB[dt], 0, 0, 0);
            }
        }
        lB += psB;
        __builtin_amdgcn_s_setprio(0);
        __syncthreads();
        cur ^= 1;
    }

    lA += __shfl_xor(lA, 16); lA += __shfl_xor(lA, 32);
    lB += __shfl_xor(lB, 16); lB += __shfl_xor(lB, 32);
    const float rlA = 1.0f / lA;
    const float rlB = 1.0f / lB;
    unsigned short* opA = Ob + ((size_t)(b*T_ + qgA))*(HQ_*HD_) + h*HD_;
    unsigned short* opB = Ob + ((size_t)(b*T_ + qgB))*(HQ_*HD_) + h*HD_;
    #pragma unroll
    for (int dt = 0; dt < 4; ++dt) {
        uint2 pa, pb;
        pa.x = (unsigned int)f2bf(oA[dt][0]*rlA) | ((unsigned int)f2bf(oA[dt][1]*rlA) << 16);
        pa.y = (unsigned int)f2bf(oA[dt][2]*rlA) | ((unsigned int)f2bf(oA[dt][3]*rlA) << 16);
        pb.x = (unsigned int)f2bf(oB[dt][0]*rlB) | ((unsigned int)f2bf(oB[dt][1]*rlB) << 16);
        pb.y = (unsigned int)f2bf(oB[dt][2]*rlB) | ((unsigned int)f2bf(oB[dt][3]*rlB) << 16);
        *(uint2*)(opA + dt*16 + quad*4) = pa;
        *(uint2*)(opB + dt*16 + quad*4) = pb;
    }
}

// ---------------- Output projection: bf16 MFMA GEMM, tri-buffered ----------
__global__ __launch_bounds__(256) void out_gemm_bf16(
    const unsigned short* __restrict__ Ab, const unsigned short* __restrict__ Wb,
    float* __restrict__ C)
{
    __shared__ unsigned short As[3][128*32];
    __shared__ unsigned short Bs[3][128*32];
    const int tid  = threadIdx.x;
    const int ln   = tid & 63;
    const int wv   = tid >> 6;
    const int wm   = (wv >> 1) * 64;
    const int wn   = (wv & 1) * 64;
    const int col  = ln & 15;
    const int quad = ln >> 4;

    // XCD-aware bijective block swizzle: 512 = 8 * 64
    const int bid = blockIdx.x;
    const int swz = (bid & 7) * 64 + (bid >> 3);
    const int n0  = (swz & 15) * 128;
    const int m0  = (swz >> 4) * 128;

    const int cg = ((tid & 3) ^ ((tid >> 3) & 3)) * 8;
    const unsigned short* aG = Ab + (size_t)(m0 + (tid>>2))*DM_ + cg;
    const unsigned short* bG = Wb + (size_t)(n0 + (tid>>2))*DM_ + cg;
    const int ck = (quad ^ ((col >> 1) & 3)) * 8;

    f32x4 acc[4][4];
    #pragma unroll
    for (int i=0;i<4;++i)
        #pragma unroll
        for (int j=0;j<4;++j) { acc[i][j][0]=0.f; acc[i][j][1]=0.f; acc[i][j][2]=0.f; acc[i][j][3]=0.f; }

    auto stage = [&](int buf, int k0) {
        unsigned short* aL = &As[buf][wv*512];
        unsigned short* bL = &Bs[buf][wv*512];
        gload16(aG + k0,                  aL);
        gload16(aG + (size_t)64*DM_ + k0, aL + 2048);
        gload16(bG + k0,                  bL);
        gload16(bG + (size_t)64*DM_ + k0, bL + 2048);
    };

    stage(0, 0);
    stage(1, 32);

    int kt = 0;
    for (int k0 = 0; k0 < DM_; k0 += 32, ++kt) {
        if (k0 + 32 < DM_) {
            asm volatile("s_waitcnt vmcnt(4)" ::: "memory");
        } else {
            asm volatile("s_waitcnt vmcnt(0)" ::: "memory");
        }
        __builtin_amdgcn_s_barrier();
        if (k0 + 64 < DM_) stage((kt+2)%3, k0 + 64);
        const unsigned short* Ac = As[kt%3];
        const unsigned short* Bc = Bs[kt%3];
        bf16x8 af[4], bfr[4];
        #pragma unroll
        for (int i=0;i<4;++i) {
            af[i]  = *(const bf16x8*)&Ac[(wm + i*16 + col)*32 + ck];
            bfr[i] = *(const bf16x8*)&Bc[(wn + i*16 + col)*32 + ck];
        }
        #pragma unroll
        for (int i=0;i<4;++i)
            #pragma unroll
            for (int j=0;j<4;++j)
                acc[i][j] = __builtin_amdgcn_mfma_f32_16x16x32_bf16(af[i], bfr[j], acc[i][j], 0, 0, 0);
    }

    #pragma unroll
    for (int i=0;i<4;++i) {
        const int m = m0 + wm + i*16 + quad*4;
        #pragma unroll
        for (int j=0;j<4;++j) {
            const int n = n0 + wn + j*16 + col;
            #pragma unroll
            for (int r=0;r<4;++r)
                C[(size_t)(m + r)*DM_ + n] = acc[i][j][r];
        }
    }
}

extern "C" void kernel_launch(void* const* d_in, const int* in_sizes, int n_in,
                              void* d_out, int out_size, void* d_ws, size_t ws_size,
                              hipStream_t stream) {
    const float* x   = (const float*)d_in[0];
    const int*   pos = (const int*)  d_in[1];
    const float* WQ  = (const float*)d_in[2];
    const float* WK  = (const float*)d_in[3];
    const float* WV  = (const float*)d_in[4];
    const float* WO  = (const float*)d_in[5];
    float* out = (float*)d_out;

    unsigned short* xb  = (unsigned short*)d_ws;
    unsigned short* Wb  = xb  + (size_t)8388608;
    unsigned short* WOb = Wb  + (size_t)6291456;
    unsigned short* Qb  = WOb + (size_t)4194304;
    unsigned short* Kb  = Qb  + (size_t)8388608;
    unsigned short* Vt  = Kb  + (size_t)2097152;
    unsigned short* Ob  = Vt  + (size_t)2097152;

    // 0) fp32 -> bf16 converts, single launch
    convert_all<<<18432, 256, 0, stream>>>(x, WQ, WK, WV, WO, (unsigned short*)d_ws);

    // 1) QKV projection -> Qb/Kb bf16 pre-RoPE, Vt f16 transposed (768 blocks, XCD-swizzled)
    qkv_gemm_bf16<<<768, 256, 0, stream>>>(xb, Wb, Qb, Kb, Vt);

    // 2) RoPE in place (Q scaled log2e/8)
    const int pairs = B_*HQ_*T_*(HD_/2) + B_*HKV_*T_*(HD_/2);
    rope_inplace<<<(pairs + 255)/256, 256, 0, stream>>>(Qb, Kb, pos);

    // 3) Causal GQA flash attention (paired Q-tiles, dbuf + pipe-interleaved)
    dim3 g3(16, B_*HQ_);
    attn_mfma<<<g3, 256, 0, stream>>>(Qb, Kb, Vt, Ob);

    // 4) Output projection -> fp32 out (512 blocks, XCD-swizzled)
    out_gemm_bf16<<<512, 256, 0, stream>>>(Ob, WOb, out);
}

// Round 4
// 302.725 us; speedup vs baseline: 1.1884x; 1.1002x over previous
//
#include <hip/hip_runtime.h>
#include <hip/hip_bf16.h>

#define B_   2
#define T_   2048
#define DM_  2048
#define HQ_  32
#define HKV_ 8
#define HD_  64

typedef __attribute__((ext_vector_type(8))) short bf16x8;
typedef __attribute__((ext_vector_type(4))) float f32x4;
typedef __fp16 f16x4 __attribute__((ext_vector_type(4)));
typedef __fp16 f16x2 __attribute__((ext_vector_type(2)));

__device__ __forceinline__ unsigned short f2bf(float f) {
    unsigned int u = __float_as_uint(f);
    u = (u + 0x7fffu + ((u >> 16) & 1u)) >> 16;   // RNE
    return (unsigned short)u;
}

__device__ __forceinline__ void gload16(const unsigned short* g, unsigned short* l) {
    __builtin_amdgcn_global_load_lds(
        (const __attribute__((address_space(1))) unsigned int*)g,
        (__attribute__((address_space(3))) unsigned int*)l, 16, 0, 0);
}

// ---------------------------------------------------------------------------
// Workspace (ushort elements, 76 MiB total):
//   xb  : 8388608   (4096,2048)      bf16 x
//   Wb  : 6291456   (3072,2048)      bf16 [WQ;WK;WV]
//   WOb : 4194304   (2048,2048)      bf16 WO
//   Qb  : 8388608   (B,HQ,T,HD)      bf16 Q (RoPE'd + scaled in qkv epilogue)
//   Kb  : 2097152   (B,HKV,T,HD)     bf16 K (RoPE'd in qkv epilogue)
//   Vt  : 2097152   (B,HKV,HD,T)     f16 V transposed
//   Ob  : 8388608   (B,T,HQ*HD)      bf16 attention out
//                    (first 512 KB reused as the cos/sin table before attn:
//                     trig[t*32+p] = {cos,sin}(pos[t]*theta^(-2p/64)) f32x2)
// ---------------------------------------------------------------------------

#define CONV_N 4718592     // float4 convert work items

// -------- merged fp32 -> bf16 convert (x, WQ, WK, WV, WO) + trig table -----
__global__ __launch_bounds__(256) void convert_all(
    const float* __restrict__ x,  const float* __restrict__ WQ,
    const float* __restrict__ WK, const float* __restrict__ WV,
    const float* __restrict__ WO, unsigned short* __restrict__ ws,
    const int* __restrict__ pos,  float* __restrict__ trig)
{
    int i = blockIdx.x*256 + threadIdx.x;
    if (i >= CONV_N) {                    // trig table: T_*32 entries
        int j = i - CONV_N;
        if (j < T_*32) {
            int t = j >> 5, p = j & 31;
            float inv = exp2f(-0.4152410118609203f * (float)p); // theta^(-2p/64)
            float ang = (float)pos[t] * inv;
            float sn, cs;
            sincosf(ang, &sn, &cs);
            *(float2*)&trig[j*2] = make_float2(cs, sn);
        }
        return;
    }
    const float* src; unsigned short* dst; int rel;
    if (i < 2097152)      { src = x;  dst = ws;                 rel = i; }
    else if (i < 3145728) { src = WQ; dst = ws + 8388608;       rel = i - 2097152; }
    else if (i < 3407872) { src = WK; dst = ws + 8388608+4194304; rel = i - 3145728; }
    else if (i < 3670016) { src = WV; dst = ws + 8388608+5242880; rel = i - 3407872; }
    else                  { src = WO; dst = ws + 14680064;      rel = i - 3670016; }
    float4 v = *(const float4*)(src + (size_t)rel*4);
    uint2 pk;
    pk.x = (unsigned int)f2bf(v.x) | ((unsigned int)f2bf(v.y) << 16);
    pk.y = (unsigned int)f2bf(v.z) | ((unsigned int)f2bf(v.w) << 16);
    *(uint2*)(dst + (size_t)rel*4) = pk;
}

// ---------------- QKV projection: bf16 MFMA GEMM, tri-buffered -------------
// R11 vs R10: K-loop unrolled by the buffer period (3): 20 triples + 4 peeled
// tail steps. All As[buf]/Bs[buf] indices are literals -> LDS bases and ds
// offsets constant-fold, killing the kt%3 magic-muls and per-iter address
// recompute that drove VALUBusy to 49%. Pipeline semantics identical to R10
// (counted vmcnt(4), depth-2 prefetch, stage-after-barrier ledger unchanged).
// RoPE is fused into the epilogue (trig table; one fewer bf16 rounding).
__global__ __launch_bounds__(256) void qkv_gemm_bf16(
    const unsigned short* __restrict__ Ab, const unsigned short* __restrict__ Wb,
    unsigned short* __restrict__ Qb, unsigned short* __restrict__ Kb,
    unsigned short* __restrict__ Vt, const float* __restrict__ trig)
{
    __shared__ unsigned short As[3][128*32];
    __shared__ unsigned short Bs[3][128*32];
    const int tid  = threadIdx.x;
    const int ln   = tid & 63;
    const int wv   = tid >> 6;
    const int wm   = (wv >> 1) * 64;
    const int wn   = (wv & 1) * 64;
    const int col  = ln & 15;
    const int quad = ln >> 4;

    // XCD-aware bijective block swizzle: 768 = 8 * 96
    const int bid = blockIdx.x;
    const int swz = (bid & 7) * 96 + (bid >> 3);
    const int n0  = (swz % 24) * 128;
    const int m0  = (swz / 24) * 128;

    // pre-swizzled global source column (involution: XOR by (row>>1)&3)
    const int cg = ((tid & 3) ^ ((tid >> 3) & 3)) * 8;
    const unsigned short* aG = Ab + (size_t)(m0 + (tid>>2))*DM_ + cg;
    const unsigned short* bG = Wb + (size_t)(n0 + (tid>>2))*DM_ + cg;
    const int ck = (quad ^ ((col >> 1) & 3)) * 8;   // swizzled read chunk

    f32x4 acc[4][4];
    #pragma unroll
    for (int i=0;i<4;++i)
        #pragma unroll
        for (int j=0;j<4;++j) { acc[i][j][0]=0.f; acc[i][j][1]=0.f; acc[i][j][2]=0.f; acc[i][j][3]=0.f; }

    auto stage = [&](int buf, int k0) {
        unsigned short* aL = &As[buf][wv*512];
        unsigned short* bL = &Bs[buf][wv*512];
        gload16(aG + k0,                  aL);
        gload16(aG + (size_t)64*DM_ + k0, aL + 2048);
        gload16(bG + k0,                  bL);
        gload16(bG + (size_t)64*DM_ + k0, bL + 2048);
    };

    auto kstep = [&](int bc, int k0v, int bstage, bool dostage, bool last) {
        if (last) asm volatile("s_waitcnt vmcnt(0)" ::: "memory");
        else      asm volatile("s_waitcnt vmcnt(4)" ::: "memory");
        __builtin_amdgcn_s_barrier();
        if (dostage) stage(bstage, k0v + 64);
        const unsigned short* Ac = As[bc];
        const unsigned short* Bc = Bs[bc];
        bf16x8 af[4], bfr[4];
        #pragma unroll
        for (int i2=0;i2<4;++i2) {
            af[i2]  = *(const bf16x8*)&Ac[(wm + i2*16 + col)*32 + ck];
            bfr[i2] = *(const bf16x8*)&Bc[(wn + i2*16 + col)*32 + ck];
        }
        #pragma unroll
        for (int i2=0;i2<4;++i2)
            #pragma unroll
            for (int j2=0;j2<4;++j2)
                acc[i2][j2] = __builtin_amdgcn_mfma_f32_16x16x32_bf16(af[i2], bfr[j2], acc[i2][j2], 0, 0, 0);
    };

    // prologue: tiles 0,1 in flight
    stage(0, 0);
    stage(1, 32);

    int k0 = 0;
    for (int rep = 0; rep < 20; ++rep) {       // kt = 0..59
        kstep(0, k0,      2, true, false);
        kstep(1, k0+32,   0, true, false);
        kstep(2, k0+64,   1, true, false);
        k0 += 96;
    }
    kstep(0, 1920, 2, true,  false);           // kt=60, stage tile 62
    kstep(1, 1952, 0, true,  false);           // kt=61, stage tile 63
    kstep(2, 1984, 1, false, false);           // kt=62
    kstep(0, 2016, 0, false, true);            // kt=63, tail drain

    // ---- epilogue: fused RoPE (Q scaled log2e/8, K unscaled), V transpose --
    const int b  = m0 >> 11;
    const int tb = m0 & 2047;
    #pragma unroll
    for (int j=0;j<4;++j) {
        const int n = n0 + wn + j*16 + col;
        if (n < 2560) {                         // Q or K: RoPE + pack
            const int d   = n & 63;
            const int p   = d >> 1;
            const bool ev = (d & 1) == 0;
            const float sc = (n < 2048) ? 0.18033688011112042f : 1.0f;  // log2e/8
            unsigned short* outp = (n < 2048)
                ? Qb + (((size_t)(b*HQ_  + (n>>6)))*T_)*HD_
                : Kb + (((size_t)(b*HKV_ + ((n-2048)>>6)))*T_)*HD_;
            #pragma unroll
            for (int i=0;i<4;++i) {
                const int t0 = tb + wm + i*16 + quad*4;
                #pragma unroll
                for (int r=0;r<4;++r) {
                    float self = acc[i][j][r];
                    float part = __shfl_xor(self, 1);
                    float2 cs  = *(const float2*)&trig[((t0 + r)*32 + p)*2];
                    float out  = ev ? (self*cs.x - part*cs.y)
                                    : (part*cs.y + self*cs.x);
                    out *= sc;
                    unsigned int pk = (unsigned int)f2bf(out);
                    unsigned int po = __shfl_xor(pk, 1);
                    if (ev)
                        *(unsigned int*)(outp + (size_t)(t0 + r)*HD_ + d) = pk | (po << 16);
                }
            }
        } else {                                // V: f16 transposed
            #pragma unroll
            for (int i=0;i<4;++i) {
                const int t = tb + wm + i*16 + quad*4;
                unsigned short* vp = Vt + (((size_t)(b*HKV_ + ((n-2560)>>6)))*HD_ + (n&63))*T_ + t;
                union { f16x2 h; unsigned int u; } c0, c1;
                c0.h = __builtin_amdgcn_cvt_pkrtz(acc[i][j][0], acc[i][j][1]);
                c1.h = __builtin_amdgcn_cvt_pkrtz(acc[i][j][2], acc[i][j][3]);
                *(unsigned int*)(vp)     = c0.u;
                *(unsigned int*)(vp + 2) = c1.u;
            }
        }
    }
}

// ---------------- MFMA flash attention, paired Q-tiles, pipelined ----------
// (unchanged from R8/R9)
__global__ __launch_bounds__(256, 2) void attn_mfma(
    const unsigned short* __restrict__ Qb, const unsigned short* __restrict__ Kb,
    const unsigned short* __restrict__ Vh, unsigned short* __restrict__ Ob)
{
    __shared__ unsigned short Ks[2][64*64];    // bf16 K rows (k), d chunks swizzled
    __shared__ unsigned short Vs[2][64*64];    // f16 V^T rows (d), k chunks swizzled

    const int tid  = threadIdx.x;
    const int lane = tid & 63;
    const int wave = tid >> 6;
    const int q16  = lane & 15;
    const int quad = lane >> 4;
    const int bxi  = blockIdx.x;          // 0..15
    const int bh   = blockIdx.y;
    const int b    = bh >> 5;
    const int h    = bh & 31;
    const int kvh  = h >> 2;
    const int qa   = bxi;                 // 0..15
    const int qbt  = 31 - bxi;            // 16..31 (qa < qbt always)
    const int qgA  = qa *64 + wave*16 + q16;
    const int qgB  = qbt*64 + wave*16 + q16;

    const unsigned short* kbase = Kb + ((size_t)(b*HKV_ + kvh))*T_*HD_;
    const unsigned short* vbase = Vh + ((size_t)(b*HKV_ + kvh))*(size_t)HD_*T_;

    const bf16x8 qA0 = *(const bf16x8*)(Qb + ((size_t)bh*T_ + qgA)*HD_ + quad*8);
    const bf16x8 qA1 = *(const bf16x8*)(Qb + ((size_t)bh*T_ + qgA)*HD_ + 32 + quad*8);
    const bf16x8 qB0 = *(const bf16x8*)(Qb + ((size_t)bh*T_ + qgB)*HD_ + quad*8);
    const bf16x8 qB1 = *(const bf16x8*)(Qb + ((size_t)bh*T_ + qgB)*HD_ + 32 + quad*8);

    f32x4 oA[4], oB[4];
    #pragma unroll
    for (int i=0;i<4;++i) {
        oA[i][0]=0.f; oA[i][1]=0.f; oA[i][2]=0.f; oA[i][3]=0.f;
        oB[i][0]=0.f; oB[i][1]=0.f; oB[i][2]=0.f; oB[i][3]=0.f;
    }
    float lA = 0.f, lB = 0.f;

    const int sr = tid >> 3;              // 0..31
    const int sj = tid & 7;               // 16B chunk
    const int sc = (sj ^ (sr & 7)) * 8;   // (sr+32)&7 == sr&7

    const int rk7 = q16 & 7;
    const int ck0 = (quad ^ rk7) * 8;
    const int ck1 = ((quad + 4) ^ rk7) * 8;

    auto smrow = [&](const f32x4 s, float& ps) -> f16x4 {
        float e0 = exp2f(s[0]), e1 = exp2f(s[1]);
        float e2 = exp2f(s[2]), e3 = exp2f(s[3]);
        ps += (e0+e1) + (e2+e3);
        union { f16x2 h[2]; f16x4 v; } c;
        c.h[0] = __builtin_amdgcn_cvt_pkrtz(e0, e1);
        c.h[1] = __builtin_amdgcn_cvt_pkrtz(e2, e3);
        return c.v;
    };

    uint4 kr0, kr1, vr0, vr1;
    kr0 = *(const uint4*)(kbase + (size_t)sr*HD_ + sj*8);
    kr1 = *(const uint4*)(kbase + (size_t)(sr+32)*HD_ + sj*8);
    vr0 = *(const uint4*)(vbase + (size_t)sr*T_ + sj*8);
    vr1 = *(const uint4*)(vbase + (size_t)(sr+32)*T_ + sj*8);
    *(uint4*)&Ks[0][sr*64 + sc]      = kr0;
    *(uint4*)&Ks[0][(sr+32)*64 + sc] = kr1;
    *(uint4*)&Vs[0][sr*64 + sc]      = vr0;
    *(uint4*)&Vs[0][(sr+32)*64 + sc] = vr1;
    kr0 = *(const uint4*)(kbase + (size_t)(64+sr)*HD_ + sj*8);
    kr1 = *(const uint4*)(kbase + (size_t)(64+sr+32)*HD_ + sj*8);
    vr0 = *(const uint4*)(vbase + (size_t)sr*T_ + 64 + sj*8);
    vr1 = *(const uint4*)(vbase + (size_t)(sr+32)*T_ + 64 + sj*8);
    __syncthreads();

    int cur = 0;

    // ---- phase 1: both Q-states (kt <= qa < qbt), branchless body ----------
    for (int kt = 0; kt <= qa; ++kt) {
        const unsigned short* KsC = Ks[cur];
        const unsigned short* VsC = Vs[cur];
        const int nxt = cur ^ 1;

        f32x4 sB[4], sA[4];
        #pragma unroll
        for (int t=0;t<4;++t) {
            sB[t][0]=0.f; sB[t][1]=0.f; sB[t][2]=0.f; sB[t][3]=0.f;
            sA[t][0]=0.f; sA[t][1]=0.f; sA[t][2]=0.f; sA[t][3]=0.f;
        }
        f16x4 pfB[4];
        float psB = 0.f, psA = 0.f;

        __builtin_amdgcn_s_setprio(1);
        #pragma unroll
        for (int t = 0; t < 4; ++t) {
            const int rk = (t*16 + q16) * 64;
            bf16x8 a0 = *(const bf16x8*)&KsC[rk + ck0];
            bf16x8 a1 = *(const bf16x8*)&KsC[rk + ck1];
            sB[t] = __builtin_amdgcn_mfma_f32_16x16x32_bf16(a0, qB0, sB[t], 0, 0, 0);
            sB[t] = __builtin_amdgcn_mfma_f32_16x16x32_bf16(a1, qB1, sB[t], 0, 0, 0);
            sA[t] = __builtin_amdgcn_mfma_f32_16x16x32_bf16(a0, qA0, sA[t], 0, 0, 0);
            sA[t] = __builtin_amdgcn_mfma_f32_16x16x32_bf16(a1, qA1, sA[t], 0, 0, 0);
            if (t > 0) pfB[t-1] = smrow(sB[t-1], psB);
        }
        *(uint4*)&Ks[nxt][sr*64 + sc]      = kr0;
        *(uint4*)&Ks[nxt][(sr+32)*64 + sc] = kr1;
        *(uint4*)&Vs[nxt][sr*64 + sc]      = vr0;
        *(uint4*)&Vs[nxt][(sr+32)*64 + sc] = vr1;
        if (kt + 1 < qbt) {
            const int kn = (kt+2)*64;
            kr0 = *(const uint4*)(kbase + (size_t)(kn+sr)*HD_ + sj*8);
            kr1 = *(const uint4*)(kbase + (size_t)(kn+sr+32)*HD_ + sj*8);
            vr0 = *(const uint4*)(vbase + (size_t)sr*T_ + kn + sj*8);
            vr1 = *(const uint4*)(vbase + (size_t)(sr+32)*T_ + kn + sj*8);
        }
        pfB[3] = smrow(sB[3], psB);
        lB += psB;

        if (kt == qa) {
            #pragma unroll
            for (int t = 0; t < 4; ++t)
                #pragma unroll
                for (int r = 0; r < 4; ++r)
                    if (kt*64 + t*16 + quad*4 + r > qgA) sA[t][r] = -1e30f;
        }

        #pragma unroll
        for (int t = 0; t < 4; ++t) {
            const int cv = ((2*t + (quad>>1)) ^ rk7) * 8 + (quad&1)*4;
            f16x4 va[4];
            #pragma unroll
            for (int dt=0;dt<4;++dt)
                va[dt] = *(const f16x4*)&VsC[(dt*16 + q16)*64 + cv];
            #pragma unroll
            for (int dt=0;dt<4;++dt)
                oB[dt] = __builtin_amdgcn_mfma_f32_16x16x16f16(va[dt], pfB[t], oB[dt], 0, 0, 0);
            f16x4 pfA = smrow(sA[t], psA);
            #pragma unroll
            for (int dt=0;dt<4;++dt)
                oA[dt] = __builtin_amdgcn_mfma_f32_16x16x16f16(va[dt], pfA, oA[dt], 0, 0, 0);
        }
        lA += psA;
        __builtin_amdgcn_s_setprio(0);
        __syncthreads();
        cur ^= 1;
    }

    // ---- phase 2: state B only (qa < kt <= qbt) ----------------------------
    for (int kt = qa+1; kt <= qbt; ++kt) {
        const unsigned short* KsC = Ks[cur];
        const unsigned short* VsC = Vs[cur];
        const int nxt = cur ^ 1;

        f32x4 sB[4];
        #pragma unroll
        for (int t=0;t<4;++t) { sB[t][0]=0.f; sB[t][1]=0.f; sB[t][2]=0.f; sB[t][3]=0.f; }

        __builtin_amdgcn_s_setprio(1);
        #pragma unroll
        for (int t = 0; t < 4; ++t) {
            const int rk = (t*16 + q16) * 64;
            bf16x8 a0 = *(const bf16x8*)&KsC[rk + ck0];
            bf16x8 a1 = *(const bf16x8*)&KsC[rk + ck1];
            sB[t] = __builtin_amdgcn_mfma_f32_16x16x32_bf16(a0, qB0, sB[t], 0, 0, 0);
            sB[t] = __builtin_amdgcn_mfma_f32_16x16x32_bf16(a1, qB1, sB[t], 0, 0, 0);
        }
        if (kt < qbt) {
            *(uint4*)&Ks[nxt][sr*64 + sc]      = kr0;
            *(uint4*)&Ks[nxt][(sr+32)*64 + sc] = kr1;
            *(uint4*)&Vs[nxt][sr*64 + sc]      = vr0;
            *(uint4*)&Vs[nxt][(sr+32)*64 + sc] = vr1;
        }
        if (kt + 1 < qbt) {
            const int kn = (kt+2)*64;
            kr0 = *(const uint4*)(kbase + (size_t)(kn+sr)*HD_ + sj*8);
            kr1 = *(const uint4*)(kbase + (size_t)(kn+sr+32)*HD_ + sj*8);
            vr0 = *(const uint4*)(vbase + (size_t)sr*T_ + kn + sj*8);
            vr1 = *(const uint4*)(vbase + (size_t)(sr+32)*T_ + kn + sj*8);
        }
        if (kt == qbt) {
            #pragma unroll
            for (int t = 0; t < 4; ++t)
                #pragma unroll
                for (int r = 0; r < 4; ++r)
                    if (kt*64 + t*16 + quad*4 + r > qgB) sB[t][r] = -1e30f;
        }

        float psB = 0.f;
        #pragma unroll
        for (int t = 0; t < 4; ++t) {
            f16x4 pfB = smrow(sB[t], psB);
            const int cv = ((2*t + (quad>>1)) ^ rk7) * 8 + (quad&1)*4;
            #pragma unroll
            for (int dt=0;dt<4;++dt) {
                f16x4 va = *(const f16x4*)&VsC[(dt*16 + q16)*64 + cv];
                oB[dt] = __builtin_amdgcn_mfma_f32_16x16x16f16(va, pfB, oB[dt], 0, 0, 0);
            }
        }
        lB += psB;
        __builtin_amdgcn_s_setprio(0);
        __syncthreads();
        cur ^= 1;
    }

    lA += __shfl_xor(lA, 16); lA += __shfl_xor(lA, 32);
    lB += __shfl_xor(lB, 16); lB += __shfl_xor(lB, 32);
    const float rlA = 1.0f / lA;
    const float rlB = 1.0f / lB;
    unsigned short* opA = Ob + ((size_t)(b*T_ + qgA))*(HQ_*HD_) + h*HD_;
    unsigned short* opB = Ob + ((size_t)(b*T_ + qgB))*(HQ_*HD_) + h*HD_;
    #pragma unroll
    for (int dt = 0; dt < 4; ++dt) {
        uint2 pa, pb;
        pa.x = (unsigned int)f2bf(oA[dt][0]*rlA) | ((unsigned int)f2bf(oA[dt][1]*rlA) << 16);
        pa.y = (unsigned int)f2bf(oA[dt][2]*rlA) | ((unsigned int)f2bf(oA[dt][3]*rlA) << 16);
        pb.x = (unsigned int)f2bf(oB[dt][0]*rlB) | ((unsigned int)f2bf(oB[dt][1]*rlB) << 16);
        pb.y = (unsigned int)f2bf(oB[dt][2]*rlB) | ((unsigned int)f2bf(oB[dt][3]*rlB) << 16);
        *(uint2*)(opA + dt*16 + quad*4) = pa;
        *(uint2*)(opB + dt*16 + quad*4) = pb;
    }
}

// ---------------- Output projection: bf16 MFMA GEMM, tri-buffered, unrolled -
__global__ __launch_bounds__(256) void out_gemm_bf16(
    const unsigned short* __restrict__ Ab, const unsigned short* __restrict__ Wb,
    float* __restrict__ C)
{
    __shared__ unsigned short As[3][128*32];
    __shared__ unsigned short Bs[3][128*32];
    const int tid  = threadIdx.x;
    const int ln   = tid & 63;
    const int wv   = tid >> 6;
    const int wm   = (wv >> 1) * 64;
    const int wn   = (wv & 1) * 64;
    const int col  = ln & 15;
    const int quad = ln >> 4;

    // XCD-aware bijective block swizzle: 512 = 8 * 64
    const int bid = blockIdx.x;
    const int swz = (bid & 7) * 64 + (bid >> 3);
    const int n0  = (swz & 15) * 128;
    const int m0  = (swz >> 4) * 128;

    const int cg = ((tid & 3) ^ ((tid >> 3) & 3)) * 8;
    const unsigned short* aG = Ab + (size_t)(m0 + (tid>>2))*DM_ + cg;
    const unsigned short* bG = Wb + (size_t)(n0 + (tid>>2))*DM_ + cg;
    const int ck = (quad ^ ((col >> 1) & 3)) * 8;

    f32x4 acc[4][4];
    #pragma unroll
    for (int i=0;i<4;++i)
        #pragma unroll
        for (int j=0;j<4;++j) { acc[i][j][0]=0.f; acc[i][j][1]=0.f; acc[i][j][2]=0.f; acc[i][j][3]=0.f; }

    auto stage = [&](int buf, int k0) {
        unsigned short* aL = &As[buf][wv*512];
        unsigned short* bL = &Bs[buf][wv*512];
        gload16(aG + k0,                  aL);
        gload16(aG + (size_t)64*DM_ + k0, aL + 2048);
        gload16(bG + k0,                  bL);
        gload16(bG + (size_t)64*DM_ + k0, bL + 2048);
    };

    auto kstep = [&](int bc, int k0v, int bstage, bool dostage, bool last) {
        if (last) asm volatile("s_waitcnt vmcnt(0)" ::: "memory");
        else      asm volatile("s_waitcnt vmcnt(4)" ::: "memory");
        __builtin_amdgcn_s_barrier();
        if (dostage) stage(bstage, k0v + 64);
        const unsigned short* Ac = As[bc];
        const unsigned short* Bc = Bs[bc];
        bf16x8 af[4], bfr[4];
        #pragma unroll
        for (int i2=0;i2<4;++i2) {
            af[i2]  = *(const bf16x8*)&Ac[(wm + i2*16 + col)*32 + ck];
            bfr[i2] = *(const bf16x8*)&Bc[(wn + i2*16 + col)*32 + ck];
        }
        #pragma unroll
        for (int i2=0;i2<4;++i2)
            #pragma unroll
            for (int j2=0;j2<4;++j2)
                acc[i2][j2] = __builtin_amdgcn_mfma_f32_16x16x32_bf16(af[i2], bfr[j2], acc[i2][j2], 0, 0, 0);
    };

    stage(0, 0);
    stage(1, 32);

    int k0 = 0;
    for (int rep = 0; rep < 20; ++rep) {
        kstep(0, k0,      2, true, false);
        kstep(1, k0+32,   0, true, false);
        kstep(2, k0+64,   1, true, false);
        k0 += 96;
    }
    kstep(0, 1920, 2, true,  false);
    kstep(1, 1952, 0, true,  false);
    kstep(2, 1984, 1, false, false);
    kstep(0, 2016, 0, false, true);

    #pragma unroll
    for (int i=0;i<4;++i) {
        const int m = m0 + wm + i*16 + quad*4;
        #pragma unroll
        for (int j=0;j<4;++j) {
            const int n = n0 + wn + j*16 + col;
            #pragma unroll
            for (int r=0;r<4;++r)
                C[(size_t)(m + r)*DM_ + n] = acc[i][j][r];
        }
    }
}

extern "C" void kernel_launch(void* const* d_in, const int* in_sizes, int n_in,
                              void* d_out, int out_size, void* d_ws, size_t ws_size,
                              hipStream_t stream) {
    const float* x   = (const float*)d_in[0];
    const int*   pos = (const int*)  d_in[1];
    const float* WQ  = (const float*)d_in[2];
    const float* WK  = (const float*)d_in[3];
    const float* WV  = (const float*)d_in[4];
    const float* WO  = (const float*)d_in[5];
    float* out = (float*)d_out;

    unsigned short* xb  = (unsigned short*)d_ws;
    unsigned short* Wb  = xb  + (size_t)8388608;
    unsigned short* WOb = Wb  + (size_t)6291456;
    unsigned short* Qb  = WOb + (size_t)4194304;
    unsigned short* Kb  = Qb  + (size_t)8388608;
    unsigned short* Vt  = Kb  + (size_t)2097152;
    unsigned short* Ob  = Vt  + (size_t)2097152;
    float* trig = (float*)Ob;    // 512 KB scratch inside Ob (dead until attn)

    // 0) fp32 -> bf16 converts + trig table, single launch
    convert_all<<<18688, 256, 0, stream>>>(x, WQ, WK, WV, WO, (unsigned short*)d_ws, pos, trig);

    // 1) QKV projection + fused RoPE -> Qb/Kb bf16, Vt f16 transposed
    qkv_gemm_bf16<<<768, 256, 0, stream>>>(xb, Wb, Qb, Kb, Vt, trig);

    // 2) Causal GQA flash attention (paired Q-tiles, dbuf + pipe-interleaved)
    dim3 g3(16, B_*HQ_);
    attn_mfma<<<g3, 256, 0, stream>>>(Qb, Kb, Vt, Ob);

    // 3) Output projection -> fp32 out (512 blocks, XCD-swizzled)
    out_gemm_bf16<<<512, 256, 0, stream>>>(Ob, WOb, out);
}